// Round 7
// baseline (187.936 us; speedup 1.0000x reference)
//
#include <hip/hip_runtime.h>
#include <hip/hip_bf16.h>
#include <math.h>

// ---------------------------------------------------------------------------
// AdvancedGCN on MI355X — round 7:
//  * gather: 32B/thread (2x uint4 per edge) + 4-edge unroll -> 8 loads in flight
//  * classifier fused into gather<32> epilogue (shfl pair-reduce), O2 gone
//  * skip/residual path bf16 (SK buffer halved)
//  * prep kernel fuses zero_counts + 3 weight transposes; edge passes int4-vec
// ---------------------------------------------------------------------------

#define BN_EPS 1e-5f

typedef __attribute__((ext_vector_type(8))) short bf16x8;
typedef __attribute__((ext_vector_type(4))) float f32x4;

static __device__ __forceinline__ float bf2f(unsigned int u16) {
    return __uint_as_float(u16 << 16);
}
static __device__ __forceinline__ unsigned short f2bf(float f) {
    unsigned int b = __float_as_uint(f);
    return (unsigned short)((b + 0x7FFFu + ((b >> 16) & 1u)) >> 16);
}
static __device__ __forceinline__ unsigned int pack2(float a, float b) {
    return (unsigned int)f2bf(a) | ((unsigned int)f2bf(b) << 16);
}
static __device__ __forceinline__ void unpack8(uint4 u, float* f) {
    f[0] = bf2f(u.x & 0xffffu); f[1] = bf2f(u.x >> 16);
    f[2] = bf2f(u.y & 0xffffu); f[3] = bf2f(u.y >> 16);
    f[4] = bf2f(u.z & 0xffffu); f[5] = bf2f(u.z >> 16);
    f[6] = bf2f(u.w & 0xffffu); f[7] = bf2f(u.w >> 16);
}
static __device__ __forceinline__ int swz(int row, int kb, int rowb) {
    return row * rowb + (kb ^ ((row & 7) << 4));
}

// ------------------------------ prep kernel --------------------------------
// section 0: zero counts; sections 1..3: Wt[m][k] bf16 builds (conv|skip)
__global__ void prep_kernel(int* __restrict__ counts, int N, int nbZero,
                            const float* __restrict__ W0,
                            const float* __restrict__ W1, const float* __restrict__ sk1W,
                            const float* __restrict__ W2, const float* __restrict__ sk2W,
                            unsigned short* __restrict__ Wt0,
                            unsigned short* __restrict__ Wt1,
                            unsigned short* __restrict__ Wt2)
{
    int b = blockIdx.x, tid = threadIdx.x;
    if (b < nbZero) {
        int i = b * 256 + tid;
        if (i < N) counts[i] = 0;
        return;
    }
    b -= nbZero;
    if (b < 64) {                       // Wt0: M=128, K=128
        int idx = b * 256 + tid;
        int m = idx >> 7, k = idx & 127;
        Wt0[idx] = f2bf(W0[(size_t)k * 128 + m]);
        return;
    }
    b -= 64;
    if (b < 64) {                       // Wt1: M=64+64, K=128
        int idx = b * 256 + tid;
        int m = idx >> 7, k = idx & 127;
        float v = (m < 64) ? W1[(size_t)k * 64 + m] : sk1W[(size_t)k * 64 + (m - 64)];
        Wt1[idx] = f2bf(v);
        return;
    }
    b -= 64;
    {                                   // Wt2: M=32+32, K=64
        int idx = b * 256 + tid;
        int m = idx >> 6, k = idx & 63;
        float v = (m < 32) ? W2[(size_t)k * 32 + m] : sk2W[(size_t)k * 32 + (m - 32)];
        Wt2[idx] = f2bf(v);
    }
}

// --------------------------- CSR build kernels -----------------------------
__global__ void rank_hist_kernel(const int* __restrict__ dst, int* __restrict__ counts,
                                 int* __restrict__ rank, int E) {
    int base = (blockIdx.x * 256 + threadIdx.x) * 4;
    if (base + 3 < E) {
        int4 d = *(const int4*)(dst + base);
        int4 r;
        r.x = atomicAdd(&counts[d.x], 1);
        r.y = atomicAdd(&counts[d.y], 1);
        r.z = atomicAdd(&counts[d.z], 1);
        r.w = atomicAdd(&counts[d.w], 1);
        *(int4*)(rank + base) = r;
    } else {
        for (int e = base; e < E; ++e) rank[e] = atomicAdd(&counts[dst[e]], 1);
    }
}

__global__ void scan_block_kernel(const int* __restrict__ counts, int* __restrict__ excl,
                                  int* __restrict__ bsum, int N) {
    __shared__ int s[256];
    int tid = threadIdx.x;
    int i = blockIdx.x * 256 + tid;
    int v = (i < N) ? counts[i] : 0;
    s[tid] = v;
    __syncthreads();
#pragma unroll
    for (int off = 1; off < 256; off <<= 1) {
        int t = (tid >= off) ? s[tid - off] : 0;
        __syncthreads();
        s[tid] += t;
        __syncthreads();
    }
    if (i < N) excl[i] = s[tid] - v;
    if (tid == 255) bsum[blockIdx.x] = s[255];
}

__global__ void scan_add_kernel(const int* __restrict__ excl, const int* __restrict__ bsum,
                                const int* __restrict__ counts,
                                int* __restrict__ rowptr, float* __restrict__ dinv,
                                int nb, int N, int E) {
    __shared__ int sb[256];
    int tid = threadIdx.x;
    int v = (tid < nb) ? bsum[tid] : 0;
    sb[tid] = v;
    __syncthreads();
#pragma unroll
    for (int off = 1; off < 256; off <<= 1) {
        int t = (tid >= off) ? sb[tid - off] : 0;
        __syncthreads();
        sb[tid] += t;
        __syncthreads();
    }
    int eb = sb[blockIdx.x] - ((blockIdx.x < nb) ? bsum[blockIdx.x] : 0);  // exclusive
    int i = blockIdx.x * 256 + tid;
    if (i < N) {
        rowptr[i] = excl[i] + eb;
        dinv[i]   = rsqrtf((float)counts[i] + 1.0f);
    }
    if (i == N) rowptr[N] = E;
}

__global__ void fill_csr_kernel(const int* __restrict__ src, const int* __restrict__ dst,
                                const int* __restrict__ rank, const int* __restrict__ rowptr,
                                int* __restrict__ csr, int E) {
    int base = (blockIdx.x * 256 + threadIdx.x) * 4;
    if (base + 3 < E) {
        int4 s = *(const int4*)(src + base);
        int4 d = *(const int4*)(dst + base);
        int4 r = *(const int4*)(rank + base);
        csr[rowptr[d.x] + r.x] = s.x;
        csr[rowptr[d.y] + r.y] = s.y;
        csr[rowptr[d.z] + r.z] = s.z;
        csr[rowptr[d.w] + r.w] = s.w;
    } else {
        for (int e = base; e < E; ++e) csr[rowptr[dst[e]] + rank[e]] = src[e];
    }
}

// ----------------------------- MFMA dual GEMM ------------------------------
// H(bf16)[N,M1] = X @ Wc ; SK(bf16)[N,M2] = X @ Wsk + skb (cols M1..M-1)
template <int K, int M1, int M2, bool IN_BF16>
__launch_bounds__(256)
__global__ void mfma_gemm_kernel(const float* __restrict__ Xf,
                                 const unsigned short* __restrict__ Xb,
                                 const unsigned short* __restrict__ Wt,
                                 const float* __restrict__ skb,
                                 unsigned short* __restrict__ H,
                                 unsigned short* __restrict__ SK, int N)
{
    constexpr int M    = M1 + M2;
    constexpr int BM   = 8192 / M;
    constexpr int WC   = M / 64;
    constexpr int ROWB = K * 2;
    constexpr int CPR  = K / 8;
    constexpr int WCH  = (M * K) / 2048;

    __shared__ unsigned char XsB[BM * K * 2];
    __shared__ unsigned char WsB[M * K * 2];

    const int tid = threadIdx.x;
    const int r0  = blockIdx.x * BM;

#pragma unroll
    for (int c = 0; c < 4; ++c) {           // BM*K/2048 == 4 for all layers
        int q   = tid + 256 * c;
        int row = q / CPR, kq = q % CPR;
        int grow = r0 + row;
        uint4 u = make_uint4(0u, 0u, 0u, 0u);
        if (IN_BF16) {
            if (grow < N) u = *(const uint4*)(Xb + (size_t)grow * K + kq * 8);
        } else {
            if (grow < N) {
                const float* p = Xf + (size_t)grow * K + kq * 8;
                float4 v0 = *(const float4*)p;
                float4 v1 = *(const float4*)(p + 4);
                u.x = pack2(v0.x, v0.y); u.y = pack2(v0.z, v0.w);
                u.z = pack2(v1.x, v1.y); u.w = pack2(v1.z, v1.w);
            }
        }
        *(uint4*)(XsB + swz(row, kq * 16, ROWB)) = u;
    }
#pragma unroll
    for (int c = 0; c < WCH; ++c) {
        int q = tid + 256 * c;
        int m = q / CPR, kq = q % CPR;
        uint4 u = *(const uint4*)(Wt + (size_t)m * K + kq * 8);
        *(uint4*)(WsB + swz(m, kq * 16, ROWB)) = u;
    }
    __syncthreads();

    const int lane = tid & 63, wid = tid >> 6;
    const int wr = wid / WC, wc = wid % WC;
    const int lrow = lane & 15;
    const int kb   = (lane >> 4) << 4;

    f32x4 acc[2][4];
#pragma unroll
    for (int fi = 0; fi < 2; ++fi)
#pragma unroll
        for (int fj = 0; fj < 4; ++fj)
            acc[fi][fj] = (f32x4){0.f, 0.f, 0.f, 0.f};

#pragma unroll
    for (int ks = 0; ks < K / 32; ++ks) {
        const int kb0 = ks * 64 + kb;
        bf16x8 a0 = *(const bf16x8*)(XsB + swz(wr * 32 +      lrow, kb0, ROWB));
        bf16x8 a1 = *(const bf16x8*)(XsB + swz(wr * 32 + 16 + lrow, kb0, ROWB));
        bf16x8 b0 = *(const bf16x8*)(WsB + swz(wc * 64 +      lrow, kb0, ROWB));
        bf16x8 b1 = *(const bf16x8*)(WsB + swz(wc * 64 + 16 + lrow, kb0, ROWB));
        bf16x8 b2 = *(const bf16x8*)(WsB + swz(wc * 64 + 32 + lrow, kb0, ROWB));
        bf16x8 b3 = *(const bf16x8*)(WsB + swz(wc * 64 + 48 + lrow, kb0, ROWB));
        acc[0][0] = __builtin_amdgcn_mfma_f32_16x16x32_bf16(a0, b0, acc[0][0], 0, 0, 0);
        acc[0][1] = __builtin_amdgcn_mfma_f32_16x16x32_bf16(a0, b1, acc[0][1], 0, 0, 0);
        acc[0][2] = __builtin_amdgcn_mfma_f32_16x16x32_bf16(a0, b2, acc[0][2], 0, 0, 0);
        acc[0][3] = __builtin_amdgcn_mfma_f32_16x16x32_bf16(a0, b3, acc[0][3], 0, 0, 0);
        acc[1][0] = __builtin_amdgcn_mfma_f32_16x16x32_bf16(a1, b0, acc[1][0], 0, 0, 0);
        acc[1][1] = __builtin_amdgcn_mfma_f32_16x16x32_bf16(a1, b1, acc[1][1], 0, 0, 0);
        acc[1][2] = __builtin_amdgcn_mfma_f32_16x16x32_bf16(a1, b2, acc[1][2], 0, 0, 0);
        acc[1][3] = __builtin_amdgcn_mfma_f32_16x16x32_bf16(a1, b3, acc[1][3], 0, 0, 0);
    }

    const int orow0 = r0 + wr * 32 + (lane >> 4) * 4;
#pragma unroll
    for (int fi = 0; fi < 2; ++fi) {
#pragma unroll
        for (int fj = 0; fj < 4; ++fj) {
            const int col = wc * 64 + fj * 16 + lrow;
            const bool conv = (M2 == 0) || (col < M1);
            const float sb = conv ? 0.f : skb[col - M1];
#pragma unroll
            for (int r = 0; r < 4; ++r) {
                const int row = orow0 + fi * 16 + r;
                if (row >= N) continue;
                const float val = acc[fi][fj][r];
                if (conv) H[(size_t)row * M1 + col] = f2bf(val);
                else      SK[(size_t)row * M2 + (col - M1)] = f2bf(val + sb);
            }
        }
    }
}

// ------------------ fused gather + self + BN + ReLU + residual -------------
// 16 channels (32B) per thread; optional fused classifier (M==32 path).
template <int M, bool OUT_BF16, bool RES_BF16, bool CLS>
__launch_bounds__(256)
__global__ void gather_bn_kernel(const int* __restrict__ rowptr, const int* __restrict__ csr,
                                 const unsigned short* __restrict__ H,
                                 const float* __restrict__ dinv,
                                 const float* __restrict__ bias,
                                 const float* __restrict__ g, const float* __restrict__ b,
                                 const float* __restrict__ m, const float* __restrict__ v,
                                 const void* __restrict__ res, void* __restrict__ out,
                                 const float* __restrict__ cW1, const float* __restrict__ cB1,
                                 const float* __restrict__ cW2, const float* __restrict__ cB2,
                                 int N)
{
    constexpr int TPN = M / 16;
    __shared__ float w1s[512];
    __shared__ float b1s[16];
    __shared__ float w2s[32];
    __shared__ float b2s[2];

    const int tid = threadIdx.x;
    if constexpr (CLS) {
        w1s[tid]       = cW1[tid];
        w1s[tid + 256] = cW1[tid + 256];
        if (tid < 16) b1s[tid] = cB1[tid];
        if (tid < 32) w2s[tid] = cW2[tid];
        if (tid < 2)  b2s[tid] = cB2[tid];
        __syncthreads();
    }

    int gid = blockIdx.x * 256 + tid;
    int n = gid / TPN;
    if (n >= N) return;
    const int c = (gid % TPN) * 16;

    // fold BN: pre = sum * s + o
    float s[16], o[16];
#pragma unroll
    for (int q = 0; q < 4; ++q) {
        float4 gv = *(const float4*)&g[c + q * 4];
        float4 bv = *(const float4*)&b[c + q * 4];
        float4 mv = *(const float4*)&m[c + q * 4];
        float4 vv = *(const float4*)&v[c + q * 4];
        float4 iv = *(const float4*)&bias[c + q * 4];
        float sv[4] = {gv.x * rsqrtf(vv.x + BN_EPS), gv.y * rsqrtf(vv.y + BN_EPS),
                       gv.z * rsqrtf(vv.z + BN_EPS), gv.w * rsqrtf(vv.w + BN_EPS)};
        float bb[4] = {bv.x, bv.y, bv.z, bv.w};
        float mm[4] = {mv.x, mv.y, mv.z, mv.w};
        float ii[4] = {iv.x, iv.y, iv.z, iv.w};
#pragma unroll
        for (int q2 = 0; q2 < 4; ++q2) {
            s[q * 4 + q2] = sv[q2];
            o[q * 4 + q2] = (ii[q2] - mm[q2]) * sv[q2] + bb[q2];
        }
    }

    const float dn = dinv[n];
    float acc[16];
    {
        uint4 h0 = *(const uint4*)&H[(size_t)n * M + c];
        uint4 h1 = *(const uint4*)&H[(size_t)n * M + c + 8];
        float hf[16];
        unpack8(h0, hf); unpack8(h1, hf + 8);
        const float d2 = dn * dn;
#pragma unroll
        for (int k = 0; k < 16; ++k) acc[k] = hf[k] * d2;
    }

    int p   = rowptr[n];
    int end = rowptr[n + 1];
    for (; p + 3 < end; p += 4) {
        int s0 = csr[p], s1 = csr[p + 1], s2 = csr[p + 2], s3 = csr[p + 3];
        uint4 a0 = *(const uint4*)&H[(size_t)s0 * M + c];
        uint4 a1 = *(const uint4*)&H[(size_t)s0 * M + c + 8];
        uint4 b0_ = *(const uint4*)&H[(size_t)s1 * M + c];
        uint4 b1_ = *(const uint4*)&H[(size_t)s1 * M + c + 8];
        uint4 c0_ = *(const uint4*)&H[(size_t)s2 * M + c];
        uint4 c1_ = *(const uint4*)&H[(size_t)s2 * M + c + 8];
        uint4 d0_ = *(const uint4*)&H[(size_t)s3 * M + c];
        uint4 d1_ = *(const uint4*)&H[(size_t)s3 * M + c + 8];
        float w0 = dinv[s0] * dn, w1 = dinv[s1] * dn;
        float w2 = dinv[s2] * dn, w3 = dinv[s3] * dn;
        float f0[16], f1[16], f2[16], f3[16];
        unpack8(a0, f0); unpack8(a1, f0 + 8);
        unpack8(b0_, f1); unpack8(b1_, f1 + 8);
        unpack8(c0_, f2); unpack8(c1_, f2 + 8);
        unpack8(d0_, f3); unpack8(d1_, f3 + 8);
#pragma unroll
        for (int k = 0; k < 16; ++k) acc[k] = fmaf(f0[k], w0, acc[k]);
#pragma unroll
        for (int k = 0; k < 16; ++k) acc[k] = fmaf(f1[k], w1, acc[k]);
#pragma unroll
        for (int k = 0; k < 16; ++k) acc[k] = fmaf(f2[k], w2, acc[k]);
#pragma unroll
        for (int k = 0; k < 16; ++k) acc[k] = fmaf(f3[k], w3, acc[k]);
    }
    for (; p < end; ++p) {
        int s0 = csr[p];
        uint4 a0 = *(const uint4*)&H[(size_t)s0 * M + c];
        uint4 a1 = *(const uint4*)&H[(size_t)s0 * M + c + 8];
        float w0 = dinv[s0] * dn;
        float f0[16];
        unpack8(a0, f0); unpack8(a1, f0 + 8);
#pragma unroll
        for (int k = 0; k < 16; ++k) acc[k] = fmaf(f0[k], w0, acc[k]);
    }

    // residual
    float rr[16];
    if constexpr (RES_BF16) {
        const unsigned short* rp = (const unsigned short*)res;
        uint4 r0 = *(const uint4*)&rp[(size_t)n * M + c];
        uint4 r1 = *(const uint4*)&rp[(size_t)n * M + c + 8];
        unpack8(r0, rr); unpack8(r1, rr + 8);
    } else {
        const float* rp = (const float*)res;
#pragma unroll
        for (int q = 0; q < 4; ++q) {
            float4 rv = *(const float4*)&rp[(size_t)n * M + c + q * 4];
            rr[q * 4 + 0] = rv.x; rr[q * 4 + 1] = rv.y;
            rr[q * 4 + 2] = rv.z; rr[q * 4 + 3] = rv.w;
        }
    }

    float outv[16];
#pragma unroll
    for (int k = 0; k < 16; ++k)
        outv[k] = fmaxf(fmaf(acc[k], s[k], o[k]), 0.f) + rr[k];

    if constexpr (CLS) {
        // partial MLP over this thread's 16 input channels, pair-reduce
        float h[16];
#pragma unroll
        for (int j = 0; j < 16; ++j) h[j] = 0.f;
#pragma unroll
        for (int k = 0; k < 16; ++k)
#pragma unroll
            for (int j = 0; j < 16; ++j)
                h[j] = fmaf(outv[k], w1s[(c + k) * 16 + j], h[j]);
#pragma unroll
        for (int j = 0; j < 16; ++j) h[j] += __shfl_xor(h[j], 1);
        float z0 = b2s[0], z1 = b2s[1];
#pragma unroll
        for (int j = 0; j < 16; ++j) {
            float r = fmaxf(h[j] + b1s[j], 0.f);
            z0 = fmaf(r, w2s[j * 2 + 0], z0);
            z1 = fmaf(r, w2s[j * 2 + 1], z1);
        }
        float mx  = fmaxf(z0, z1);
        float lse = mx + logf(expf(z0 - mx) + expf(z1 - mx));
        if ((tid & 1) == 0) {
            float* op = (float*)out;
            op[(size_t)n * 2 + 0] = z0 - lse;
            op[(size_t)n * 2 + 1] = z1 - lse;
        }
    } else if constexpr (OUT_BF16) {
        unsigned short* op = (unsigned short*)out;
        uint4 u0, u1;
        u0.x = pack2(outv[0], outv[1]);  u0.y = pack2(outv[2], outv[3]);
        u0.z = pack2(outv[4], outv[5]);  u0.w = pack2(outv[6], outv[7]);
        u1.x = pack2(outv[8], outv[9]);  u1.y = pack2(outv[10], outv[11]);
        u1.z = pack2(outv[12], outv[13]); u1.w = pack2(outv[14], outv[15]);
        *(uint4*)&op[(size_t)n * M + c]     = u0;
        *(uint4*)&op[(size_t)n * M + c + 8] = u1;
    } else {
        float* op = (float*)out;
#pragma unroll
        for (int q = 0; q < 4; ++q)
            *(float4*)&op[(size_t)n * M + c + q * 4] =
                make_float4(outv[q * 4], outv[q * 4 + 1], outv[q * 4 + 2], outv[q * 4 + 3]);
    }
}

// ------------------------------- launch ------------------------------------
extern "C" void kernel_launch(void* const* d_in, const int* in_sizes, int n_in,
                              void* d_out, int out_size, void* d_ws, size_t ws_size,
                              hipStream_t stream)
{
    const float* x    = (const float*)d_in[0];
    const int*   edge = (const int*)d_in[1];
    const float* W0   = (const float*)d_in[2];
    const float* b0v  = (const float*)d_in[3];
    const float* bn0g = (const float*)d_in[4];
    const float* bn0b = (const float*)d_in[5];
    const float* bn0m = (const float*)d_in[6];
    const float* bn0v = (const float*)d_in[7];
    const float* W1   = (const float*)d_in[8];
    const float* b1v  = (const float*)d_in[9];
    const float* bn1g = (const float*)d_in[10];
    const float* bn1b = (const float*)d_in[11];
    const float* bn1m = (const float*)d_in[12];
    const float* bn1v = (const float*)d_in[13];
    const float* sk1W = (const float*)d_in[14];
    const float* sk1b = (const float*)d_in[15];
    const float* W2   = (const float*)d_in[16];
    const float* b2v  = (const float*)d_in[17];
    const float* bn2g = (const float*)d_in[18];
    const float* bn2b = (const float*)d_in[19];
    const float* bn2m = (const float*)d_in[20];
    const float* bn2v = (const float*)d_in[21];
    const float* sk2W = (const float*)d_in[22];
    const float* sk2b = (const float*)d_in[23];
    const float* c1W  = (const float*)d_in[24];
    const float* c1b  = (const float*)d_in[25];
    const float* c2W  = (const float*)d_in[26];
    const float* c2b  = (const float*)d_in[27];

    const int N = in_sizes[0] / 128;
    const int E = in_sizes[1] / 2;
    const int* src = edge;
    const int* dst = edge + E;

    char*  ws  = (char*)d_ws;
    size_t off = 0;
    auto alloc = [&](size_t bytes) -> char* {
        char* p = ws + off;
        off += (bytes + 255) & ~(size_t)255;
        return p;
    };
    float*          dinv   = (float*)alloc((size_t)N * 4);
    int*            counts = (int*)  alloc((size_t)N * 4);
    int*            excl   = (int*)  alloc((size_t)N * 4);
    int*            rowptr = (int*)  alloc((size_t)(N + 1) * 4);
    int*            bsum   = (int*)  alloc(256 * 4);
    int*            rank   = (int*)  alloc((size_t)E * 4);
    int*            csr    = (int*)  alloc((size_t)E * 4);
    unsigned short* Hb     = (unsigned short*)alloc((size_t)N * 128 * 2);
    unsigned short* SKb    = (unsigned short*)alloc((size_t)N * 64 * 2);
    unsigned short* Q0     = (unsigned short*)alloc((size_t)N * 128 * 2);
    unsigned short* P1     = (unsigned short*)alloc((size_t)N * 64 * 2);
    unsigned short* Wt0    = (unsigned short*)alloc(128 * 128 * 2);
    unsigned short* Wt1    = (unsigned short*)alloc(128 * 128 * 2);
    unsigned short* Wt2    = (unsigned short*)alloc(64 * 64 * 2);
    (void)ws_size; (void)n_in; (void)out_size;

    dim3 blk(256);
    auto cdiv = [](int a, int b) { return (a + b - 1) / b; };
    const int nbN = cdiv(N, 256);

    // ---- prep: zero counts + weight transposes ----
    prep_kernel<<<nbN + 64 + 64 + 16, blk, 0, stream>>>(
        counts, N, nbN, W0, W1, sk1W, W2, sk2W, Wt0, Wt1, Wt2);

    // ---- CSR build (by dst) + dinv ----
    rank_hist_kernel<<<cdiv(E, 1024), blk, 0, stream>>>(dst, counts, rank, E);
    scan_block_kernel<<<nbN, blk, 0, stream>>>(counts, excl, bsum, N);
    scan_add_kernel<<<cdiv(N + 1, 256), blk, 0, stream>>>(excl, bsum, counts, rowptr, dinv, nbN, N, E);
    fill_csr_kernel<<<cdiv(E, 1024), blk, 0, stream>>>(src, dst, rank, rowptr, csr, E);

    // ---- layer 0: 128 -> 128, residual = x (f32) ----
    mfma_gemm_kernel<128, 128, 0, false><<<cdiv(N, 64), blk, 0, stream>>>(
        x, nullptr, Wt0, nullptr, Hb, nullptr, N);
    gather_bn_kernel<128, true, false, false><<<cdiv(N * 8, 256), blk, 0, stream>>>(
        rowptr, csr, Hb, dinv, b0v, bn0g, bn0b, bn0m, bn0v, x, Q0,
        nullptr, nullptr, nullptr, nullptr, N);

    // ---- layer 1: 128 -> 64, skip fused (bf16) ----
    mfma_gemm_kernel<128, 64, 64, true><<<cdiv(N, 64), blk, 0, stream>>>(
        nullptr, Q0, Wt1, sk1b, Hb, SKb, N);
    gather_bn_kernel<64, true, true, false><<<cdiv(N * 4, 256), blk, 0, stream>>>(
        rowptr, csr, Hb, dinv, b1v, bn1g, bn1b, bn1m, bn1v, SKb, P1,
        nullptr, nullptr, nullptr, nullptr, N);

    // ---- layer 2: 64 -> 32, skip fused (bf16), classifier fused ----
    mfma_gemm_kernel<64, 32, 32, true><<<cdiv(N, 128), blk, 0, stream>>>(
        nullptr, P1, Wt2, sk2b, Hb, SKb, N);
    gather_bn_kernel<32, false, true, true><<<cdiv(N * 2, 256), blk, 0, stream>>>(
        rowptr, csr, Hb, dinv, b2v, bn2g, bn2b, bn2m, bn2v, SKb, d_out,
        c1W, c1b, c2W, c2b, N);
}

// Round 8
// 181.576 us; speedup vs baseline: 1.0350x; 1.0350x over previous
//
#include <hip/hip_runtime.h>
#include <hip/hip_bf16.h>
#include <math.h>

// ---------------------------------------------------------------------------
// AdvancedGCN on MI355X — round 8:
//  * gather back to 8ch/thread (TLP > ILP for latency-bound gather; r7 lesson)
//  * BN scale/offset folded once in prep (gather reads 2 arrays, not 5)
//  * rank_hist fused into GEMM0 launch as concurrent extra blocks
// ---------------------------------------------------------------------------

#define BN_EPS 1e-5f

typedef __attribute__((ext_vector_type(8))) short bf16x8;
typedef __attribute__((ext_vector_type(4))) float f32x4;

static __device__ __forceinline__ float bf2f(unsigned int u16) {
    return __uint_as_float(u16 << 16);
}
static __device__ __forceinline__ unsigned short f2bf(float f) {
    unsigned int b = __float_as_uint(f);
    return (unsigned short)((b + 0x7FFFu + ((b >> 16) & 1u)) >> 16);
}
static __device__ __forceinline__ unsigned int pack2(float a, float b) {
    return (unsigned int)f2bf(a) | ((unsigned int)f2bf(b) << 16);
}
static __device__ __forceinline__ void unpack8(uint4 u, float* f) {
    f[0] = bf2f(u.x & 0xffffu); f[1] = bf2f(u.x >> 16);
    f[2] = bf2f(u.y & 0xffffu); f[3] = bf2f(u.y >> 16);
    f[4] = bf2f(u.z & 0xffffu); f[5] = bf2f(u.z >> 16);
    f[6] = bf2f(u.w & 0xffffu); f[7] = bf2f(u.w >> 16);
}
static __device__ __forceinline__ int swz(int row, int kb, int rowb) {
    return row * rowb + (kb ^ ((row & 7) << 4));
}

// ------------------------------ prep kernel --------------------------------
// sections: [0,nbZero): zero counts | 64 blocks Wt0 | 64 Wt1 | 16 Wt2 |
//           1 block: folded BN scale/offset for all 3 layers (224 channels)
__global__ void prep_kernel(int* __restrict__ counts, int N, int nbZero,
                            const float* __restrict__ W0,
                            const float* __restrict__ W1, const float* __restrict__ sk1W,
                            const float* __restrict__ W2, const float* __restrict__ sk2W,
                            unsigned short* __restrict__ Wt0,
                            unsigned short* __restrict__ Wt1,
                            unsigned short* __restrict__ Wt2,
                            const float* __restrict__ b0v, const float* __restrict__ bn0g,
                            const float* __restrict__ bn0b, const float* __restrict__ bn0m,
                            const float* __restrict__ bn0v,
                            const float* __restrict__ b1v, const float* __restrict__ bn1g,
                            const float* __restrict__ bn1b, const float* __restrict__ bn1m,
                            const float* __restrict__ bn1v,
                            const float* __restrict__ b2v, const float* __restrict__ bn2g,
                            const float* __restrict__ bn2b, const float* __restrict__ bn2m,
                            const float* __restrict__ bn2v,
                            float* __restrict__ bnS, float* __restrict__ bnO)
{
    int b = blockIdx.x, tid = threadIdx.x;
    if (b < nbZero) {
        int i = b * 256 + tid;
        if (i < N) counts[i] = 0;
        return;
    }
    b -= nbZero;
    if (b < 64) {                       // Wt0: M=128, K=128
        int idx = b * 256 + tid;
        int m = idx >> 7, k = idx & 127;
        Wt0[idx] = f2bf(W0[(size_t)k * 128 + m]);
        return;
    }
    b -= 64;
    if (b < 64) {                       // Wt1: M=64+64, K=128
        int idx = b * 256 + tid;
        int m = idx >> 7, k = idx & 127;
        float v = (m < 64) ? W1[(size_t)k * 64 + m] : sk1W[(size_t)k * 64 + (m - 64)];
        Wt1[idx] = f2bf(v);
        return;
    }
    b -= 64;
    if (b < 16) {                       // Wt2: M=32+32, K=64
        int idx = b * 256 + tid;
        int m = idx >> 6, k = idx & 63;
        float v = (m < 32) ? W2[(size_t)k * 32 + m] : sk2W[(size_t)k * 32 + (m - 32)];
        Wt2[idx] = f2bf(v);
        return;
    }
    // folded BN: bnS = g*rsqrt(v+eps); bnO = (bias - m)*bnS + b
    if (tid < 128) {
        float s = bn0g[tid] * rsqrtf(bn0v[tid] + BN_EPS);
        bnS[tid] = s;
        bnO[tid] = (b0v[tid] - bn0m[tid]) * s + bn0b[tid];
    } else if (tid < 192) {
        int c = tid - 128;
        float s = bn1g[c] * rsqrtf(bn1v[c] + BN_EPS);
        bnS[tid] = s;
        bnO[tid] = (b1v[c] - bn1m[c]) * s + bn1b[c];
    } else if (tid < 224) {
        int c = tid - 192;
        float s = bn2g[c] * rsqrtf(bn2v[c] + BN_EPS);
        bnS[tid] = s;
        bnO[tid] = (b2v[c] - bn2m[c]) * s + bn2b[c];
    }
}

// --------------------------- CSR build kernels -----------------------------
__global__ void scan_block_kernel(const int* __restrict__ counts, int* __restrict__ excl,
                                  int* __restrict__ bsum, int N) {
    __shared__ int s[256];
    int tid = threadIdx.x;
    int i = blockIdx.x * 256 + tid;
    int v = (i < N) ? counts[i] : 0;
    s[tid] = v;
    __syncthreads();
#pragma unroll
    for (int off = 1; off < 256; off <<= 1) {
        int t = (tid >= off) ? s[tid - off] : 0;
        __syncthreads();
        s[tid] += t;
        __syncthreads();
    }
    if (i < N) excl[i] = s[tid] - v;
    if (tid == 255) bsum[blockIdx.x] = s[255];
}

__global__ void scan_add_kernel(const int* __restrict__ excl, const int* __restrict__ bsum,
                                const int* __restrict__ counts,
                                int* __restrict__ rowptr, float* __restrict__ dinv,
                                int nb, int N, int E) {
    __shared__ int sb[256];
    int tid = threadIdx.x;
    int v = (tid < nb) ? bsum[tid] : 0;
    sb[tid] = v;
    __syncthreads();
#pragma unroll
    for (int off = 1; off < 256; off <<= 1) {
        int t = (tid >= off) ? sb[tid - off] : 0;
        __syncthreads();
        sb[tid] += t;
        __syncthreads();
    }
    int eb = sb[blockIdx.x] - ((blockIdx.x < nb) ? bsum[blockIdx.x] : 0);  // exclusive
    int i = blockIdx.x * 256 + tid;
    if (i < N) {
        rowptr[i] = excl[i] + eb;
        dinv[i]   = rsqrtf((float)counts[i] + 1.0f);
    }
    if (i == N) rowptr[N] = E;
}

__global__ void fill_csr_kernel(const int* __restrict__ src, const int* __restrict__ dst,
                                const int* __restrict__ rank, const int* __restrict__ rowptr,
                                int* __restrict__ csr, int E) {
    int base = (blockIdx.x * 256 + threadIdx.x) * 4;
    if (base + 3 < E) {
        int4 s = *(const int4*)(src + base);
        int4 d = *(const int4*)(dst + base);
        int4 r = *(const int4*)(rank + base);
        csr[rowptr[d.x] + r.x] = s.x;
        csr[rowptr[d.y] + r.y] = s.y;
        csr[rowptr[d.z] + r.z] = s.z;
        csr[rowptr[d.w] + r.w] = s.w;
    } else {
        for (int e = base; e < E; ++e) csr[rowptr[dst[e]] + rank[e]] = src[e];
    }
}

// --------------------------- MFMA GEMM body --------------------------------
// H(bf16)[N,M1] = X @ Wc ; SK(bf16)[N,M2] = X @ Wsk + skb (cols M1..M-1)
template <int K, int M1, int M2, bool IN_BF16>
static __device__ __forceinline__ void gemm_body(
    const float* __restrict__ Xf, const unsigned short* __restrict__ Xb,
    const unsigned short* __restrict__ Wt, const float* __restrict__ skb,
    unsigned short* __restrict__ H, unsigned short* __restrict__ SK, int N,
    unsigned char* XsB, unsigned char* WsB, int bid)
{
    constexpr int M    = M1 + M2;
    constexpr int BM   = 8192 / M;
    constexpr int WC   = M / 64;
    constexpr int ROWB = K * 2;
    constexpr int CPR  = K / 8;
    constexpr int WCH  = (M * K) / 2048;

    const int tid = threadIdx.x;
    const int r0  = bid * BM;

#pragma unroll
    for (int c = 0; c < 4; ++c) {           // BM*K/2048 == 4 for all layers
        int q   = tid + 256 * c;
        int row = q / CPR, kq = q % CPR;
        int grow = r0 + row;
        uint4 u = make_uint4(0u, 0u, 0u, 0u);
        if (IN_BF16) {
            if (grow < N) u = *(const uint4*)(Xb + (size_t)grow * K + kq * 8);
        } else {
            if (grow < N) {
                const float* p = Xf + (size_t)grow * K + kq * 8;
                float4 v0 = *(const float4*)p;
                float4 v1 = *(const float4*)(p + 4);
                u.x = pack2(v0.x, v0.y); u.y = pack2(v0.z, v0.w);
                u.z = pack2(v1.x, v1.y); u.w = pack2(v1.z, v1.w);
            }
        }
        *(uint4*)(XsB + swz(row, kq * 16, ROWB)) = u;
    }
#pragma unroll
    for (int c = 0; c < WCH; ++c) {
        int q = tid + 256 * c;
        int m = q / CPR, kq = q % CPR;
        uint4 u = *(const uint4*)(Wt + (size_t)m * K + kq * 8);
        *(uint4*)(WsB + swz(m, kq * 16, ROWB)) = u;
    }
    __syncthreads();

    const int lane = tid & 63, wid = tid >> 6;
    const int wr = wid / WC, wc = wid % WC;
    const int lrow = lane & 15;
    const int kb   = (lane >> 4) << 4;

    f32x4 acc[2][4];
#pragma unroll
    for (int fi = 0; fi < 2; ++fi)
#pragma unroll
        for (int fj = 0; fj < 4; ++fj)
            acc[fi][fj] = (f32x4){0.f, 0.f, 0.f, 0.f};

#pragma unroll
    for (int ks = 0; ks < K / 32; ++ks) {
        const int kb0 = ks * 64 + kb;
        bf16x8 a0 = *(const bf16x8*)(XsB + swz(wr * 32 +      lrow, kb0, ROWB));
        bf16x8 a1 = *(const bf16x8*)(XsB + swz(wr * 32 + 16 + lrow, kb0, ROWB));
        bf16x8 b0 = *(const bf16x8*)(WsB + swz(wc * 64 +      lrow, kb0, ROWB));
        bf16x8 b1 = *(const bf16x8*)(WsB + swz(wc * 64 + 16 + lrow, kb0, ROWB));
        bf16x8 b2 = *(const bf16x8*)(WsB + swz(wc * 64 + 32 + lrow, kb0, ROWB));
        bf16x8 b3 = *(const bf16x8*)(WsB + swz(wc * 64 + 48 + lrow, kb0, ROWB));
        acc[0][0] = __builtin_amdgcn_mfma_f32_16x16x32_bf16(a0, b0, acc[0][0], 0, 0, 0);
        acc[0][1] = __builtin_amdgcn_mfma_f32_16x16x32_bf16(a0, b1, acc[0][1], 0, 0, 0);
        acc[0][2] = __builtin_amdgcn_mfma_f32_16x16x32_bf16(a0, b2, acc[0][2], 0, 0, 0);
        acc[0][3] = __builtin_amdgcn_mfma_f32_16x16x32_bf16(a0, b3, acc[0][3], 0, 0, 0);
        acc[1][0] = __builtin_amdgcn_mfma_f32_16x16x32_bf16(a1, b0, acc[1][0], 0, 0, 0);
        acc[1][1] = __builtin_amdgcn_mfma_f32_16x16x32_bf16(a1, b1, acc[1][1], 0, 0, 0);
        acc[1][2] = __builtin_amdgcn_mfma_f32_16x16x32_bf16(a1, b2, acc[1][2], 0, 0, 0);
        acc[1][3] = __builtin_amdgcn_mfma_f32_16x16x32_bf16(a1, b3, acc[1][3], 0, 0, 0);
    }

    const int orow0 = r0 + wr * 32 + (lane >> 4) * 4;
#pragma unroll
    for (int fi = 0; fi < 2; ++fi) {
#pragma unroll
        for (int fj = 0; fj < 4; ++fj) {
            const int col = wc * 64 + fj * 16 + lrow;
            const bool conv = (M2 == 0) || (col < M1);
            const float sb = conv ? 0.f : skb[col - M1];
#pragma unroll
            for (int r = 0; r < 4; ++r) {
                const int row = orow0 + fi * 16 + r;
                if (row >= N) continue;
                const float val = acc[fi][fj][r];
                if (conv) H[(size_t)row * M1 + col] = f2bf(val);
                else      SK[(size_t)row * M2 + (col - M1)] = f2bf(val + sb);
            }
        }
    }
}

// plain GEMM kernels (layers 1,2)
template <int K, int M1, int M2, bool IN_BF16>
__launch_bounds__(256)
__global__ void mfma_gemm_kernel(const float* __restrict__ Xf,
                                 const unsigned short* __restrict__ Xb,
                                 const unsigned short* __restrict__ Wt,
                                 const float* __restrict__ skb,
                                 unsigned short* __restrict__ H,
                                 unsigned short* __restrict__ SK, int N)
{
    constexpr int M  = M1 + M2;
    constexpr int BM = 8192 / M;
    __shared__ unsigned char XsB[BM * K * 2];
    __shared__ unsigned char WsB[M * K * 2];
    gemm_body<K, M1, M2, IN_BF16>(Xf, Xb, Wt, skb, H, SK, N, XsB, WsB, blockIdx.x);
}

// layer-0 GEMM with rank_hist fused as extra blocks (independent work)
__launch_bounds__(256)
__global__ void gemm0_rank_kernel(const float* __restrict__ X,
                                  const unsigned short* __restrict__ Wt,
                                  unsigned short* __restrict__ H, int N, int G0,
                                  const int* __restrict__ dst, int* __restrict__ counts,
                                  int* __restrict__ rank, int E)
{
    __shared__ unsigned char XsB[64 * 128 * 2];
    __shared__ unsigned char WsB[128 * 128 * 2];
    if (blockIdx.x < G0) {
        gemm_body<128, 128, 0, false>(X, nullptr, Wt, nullptr, H, nullptr, N,
                                      XsB, WsB, blockIdx.x);
        return;
    }
    int base = ((blockIdx.x - G0) * 256 + threadIdx.x) * 4;
    if (base + 3 < E) {
        int4 d = *(const int4*)(dst + base);
        int4 r;
        r.x = atomicAdd(&counts[d.x], 1);
        r.y = atomicAdd(&counts[d.y], 1);
        r.z = atomicAdd(&counts[d.z], 1);
        r.w = atomicAdd(&counts[d.w], 1);
        *(int4*)(rank + base) = r;
    } else {
        for (int e = base; e < E; ++e) rank[e] = atomicAdd(&counts[dst[e]], 1);
    }
}

// ------------------ fused gather + self + BN + ReLU + residual -------------
// 8 channels (16B) per thread; optional fused classifier (M==32).
template <int M, bool OUT_BF16, bool RES_BF16, bool CLS>
__launch_bounds__(256)
__global__ void gather_bn_kernel(const int* __restrict__ rowptr, const int* __restrict__ csr,
                                 const unsigned short* __restrict__ H,
                                 const float* __restrict__ dinv,
                                 const float* __restrict__ bnS, const float* __restrict__ bnO,
                                 const void* __restrict__ res, void* __restrict__ out,
                                 const float* __restrict__ cW1, const float* __restrict__ cB1,
                                 const float* __restrict__ cW2, const float* __restrict__ cB2,
                                 int N)
{
    constexpr int TPN = M / 8;
    __shared__ float w1s[512];
    __shared__ float b1s[16];
    __shared__ float w2s[32];
    __shared__ float b2s[2];

    const int tid = threadIdx.x;
    if constexpr (CLS) {
        w1s[tid]       = cW1[tid];
        w1s[tid + 256] = cW1[tid + 256];
        if (tid < 16) b1s[tid] = cB1[tid];
        if (tid < 32) w2s[tid] = cW2[tid];
        if (tid < 2)  b2s[tid] = cB2[tid];
        __syncthreads();
    }

    int gid = blockIdx.x * 256 + tid;
    int n = gid / TPN;
    if (n >= N) return;
    const int c = (gid % TPN) * 8;

    float s[8], o[8];
    {
        float4 sa = *(const float4*)&bnS[c], sb_ = *(const float4*)&bnS[c + 4];
        float4 oa = *(const float4*)&bnO[c], ob_ = *(const float4*)&bnO[c + 4];
        s[0] = sa.x; s[1] = sa.y; s[2] = sa.z; s[3] = sa.w;
        s[4] = sb_.x; s[5] = sb_.y; s[6] = sb_.z; s[7] = sb_.w;
        o[0] = oa.x; o[1] = oa.y; o[2] = oa.z; o[3] = oa.w;
        o[4] = ob_.x; o[5] = ob_.y; o[6] = ob_.z; o[7] = ob_.w;
    }

    const float dn = dinv[n];
    float acc[8], hf[8];
    uint4 hs = *(const uint4*)&H[(size_t)n * M + c];
    unpack8(hs, hf);
    const float d2 = dn * dn;
#pragma unroll
    for (int k = 0; k < 8; ++k) acc[k] = hf[k] * d2;

    int p   = rowptr[n];
    int end = rowptr[n + 1];
    for (; p + 3 < end; p += 4) {
        int s0 = csr[p], s1 = csr[p + 1], s2 = csr[p + 2], s3 = csr[p + 3];
        uint4 h0 = *(const uint4*)&H[(size_t)s0 * M + c];
        uint4 h1 = *(const uint4*)&H[(size_t)s1 * M + c];
        uint4 h2 = *(const uint4*)&H[(size_t)s2 * M + c];
        uint4 h3 = *(const uint4*)&H[(size_t)s3 * M + c];
        float w0 = dinv[s0] * dn, w1 = dinv[s1] * dn;
        float w2 = dinv[s2] * dn, w3 = dinv[s3] * dn;
        float f0[8], f1[8], f2[8], f3[8];
        unpack8(h0, f0); unpack8(h1, f1); unpack8(h2, f2); unpack8(h3, f3);
#pragma unroll
        for (int k = 0; k < 8; ++k) acc[k] = fmaf(f0[k], w0, acc[k]);
#pragma unroll
        for (int k = 0; k < 8; ++k) acc[k] = fmaf(f1[k], w1, acc[k]);
#pragma unroll
        for (int k = 0; k < 8; ++k) acc[k] = fmaf(f2[k], w2, acc[k]);
#pragma unroll
        for (int k = 0; k < 8; ++k) acc[k] = fmaf(f3[k], w3, acc[k]);
    }
    for (; p < end; ++p) {
        int s0 = csr[p];
        uint4 h0 = *(const uint4*)&H[(size_t)s0 * M + c];
        float w0 = dinv[s0] * dn;
        float f0[8];
        unpack8(h0, f0);
#pragma unroll
        for (int k = 0; k < 8; ++k) acc[k] = fmaf(f0[k], w0, acc[k]);
    }

    // residual
    float rr[8];
    if constexpr (RES_BF16) {
        const unsigned short* rp = (const unsigned short*)res;
        uint4 r0 = *(const uint4*)&rp[(size_t)n * M + c];
        unpack8(r0, rr);
    } else {
        const float* rp = (const float*)res;
        float4 r0 = *(const float4*)&rp[(size_t)n * M + c];
        float4 r1 = *(const float4*)&rp[(size_t)n * M + c + 4];
        rr[0] = r0.x; rr[1] = r0.y; rr[2] = r0.z; rr[3] = r0.w;
        rr[4] = r1.x; rr[5] = r1.y; rr[6] = r1.z; rr[7] = r1.w;
    }

    float outv[8];
#pragma unroll
    for (int k = 0; k < 8; ++k)
        outv[k] = fmaxf(fmaf(acc[k], s[k], o[k]), 0.f) + rr[k];

    if constexpr (CLS) {
        // partial 32->16 MLP over this thread's 8 channels; 4-lane reduce
        float h[16];
#pragma unroll
        for (int j = 0; j < 16; ++j) h[j] = 0.f;
#pragma unroll
        for (int k = 0; k < 8; ++k)
#pragma unroll
            for (int j = 0; j < 16; ++j)
                h[j] = fmaf(outv[k], w1s[(c + k) * 16 + j], h[j]);
#pragma unroll
        for (int j = 0; j < 16; ++j) {
            h[j] += __shfl_xor(h[j], 1);
            h[j] += __shfl_xor(h[j], 2);
        }
        float z0 = b2s[0], z1 = b2s[1];
#pragma unroll
        for (int j = 0; j < 16; ++j) {
            float r = fmaxf(h[j] + b1s[j], 0.f);
            z0 = fmaf(r, w2s[j * 2 + 0], z0);
            z1 = fmaf(r, w2s[j * 2 + 1], z1);
        }
        if ((tid & 3) == 0) {
            float mx  = fmaxf(z0, z1);
            float lse = mx + logf(expf(z0 - mx) + expf(z1 - mx));
            float* op = (float*)out;
            op[(size_t)n * 2 + 0] = z0 - lse;
            op[(size_t)n * 2 + 1] = z1 - lse;
        }
    } else if constexpr (OUT_BF16) {
        unsigned short* op = (unsigned short*)out;
        uint4 u;
        u.x = pack2(outv[0], outv[1]); u.y = pack2(outv[2], outv[3]);
        u.z = pack2(outv[4], outv[5]); u.w = pack2(outv[6], outv[7]);
        *(uint4*)&op[(size_t)n * M + c] = u;
    } else {
        float* op = (float*)out;
        *(float4*)&op[(size_t)n * M + c]     = make_float4(outv[0], outv[1], outv[2], outv[3]);
        *(float4*)&op[(size_t)n * M + c + 4] = make_float4(outv[4], outv[5], outv[6], outv[7]);
    }
}

// ------------------------------- launch ------------------------------------
extern "C" void kernel_launch(void* const* d_in, const int* in_sizes, int n_in,
                              void* d_out, int out_size, void* d_ws, size_t ws_size,
                              hipStream_t stream)
{
    const float* x    = (const float*)d_in[0];
    const int*   edge = (const int*)d_in[1];
    const float* W0   = (const float*)d_in[2];
    const float* b0v  = (const float*)d_in[3];
    const float* bn0g = (const float*)d_in[4];
    const float* bn0b = (const float*)d_in[5];
    const float* bn0m = (const float*)d_in[6];
    const float* bn0v = (const float*)d_in[7];
    const float* W1   = (const float*)d_in[8];
    const float* b1v  = (const float*)d_in[9];
    const float* bn1g = (const float*)d_in[10];
    const float* bn1b = (const float*)d_in[11];
    const float* bn1m = (const float*)d_in[12];
    const float* bn1v = (const float*)d_in[13];
    const float* sk1W = (const float*)d_in[14];
    const float* sk1b = (const float*)d_in[15];
    const float* W2   = (const float*)d_in[16];
    const float* b2v  = (const float*)d_in[17];
    const float* bn2g = (const float*)d_in[18];
    const float* bn2b = (const float*)d_in[19];
    const float* bn2m = (const float*)d_in[20];
    const float* bn2v = (const float*)d_in[21];
    const float* sk2W = (const float*)d_in[22];
    const float* sk2b = (const float*)d_in[23];
    const float* c1W  = (const float*)d_in[24];
    const float* c1b  = (const float*)d_in[25];
    const float* c2W  = (const float*)d_in[26];
    const float* c2b  = (const float*)d_in[27];

    const int N = in_sizes[0] / 128;
    const int E = in_sizes[1] / 2;
    const int* src = edge;
    const int* dst = edge + E;

    char*  ws  = (char*)d_ws;
    size_t off = 0;
    auto alloc = [&](size_t bytes) -> char* {
        char* p = ws + off;
        off += (bytes + 255) & ~(size_t)255;
        return p;
    };
    float*          dinv   = (float*)alloc((size_t)N * 4);
    int*            counts = (int*)  alloc((size_t)N * 4);
    int*            excl   = (int*)  alloc((size_t)N * 4);
    int*            rowptr = (int*)  alloc((size_t)(N + 1) * 4);
    int*            bsum   = (int*)  alloc(256 * 4);
    int*            rank   = (int*)  alloc((size_t)E * 4);
    int*            csr    = (int*)  alloc((size_t)E * 4);
    unsigned short* Hb     = (unsigned short*)alloc((size_t)N * 128 * 2);
    unsigned short* SKb    = (unsigned short*)alloc((size_t)N * 64 * 2);
    unsigned short* Q0     = (unsigned short*)alloc((size_t)N * 128 * 2);
    unsigned short* P1     = (unsigned short*)alloc((size_t)N * 64 * 2);
    unsigned short* Wt0    = (unsigned short*)alloc(128 * 128 * 2);
    unsigned short* Wt1    = (unsigned short*)alloc(128 * 128 * 2);
    unsigned short* Wt2    = (unsigned short*)alloc(64 * 64 * 2);
    float*          bnS    = (float*)alloc(224 * 4);
    float*          bnO    = (float*)alloc(224 * 4);
    (void)ws_size; (void)n_in; (void)out_size;

    dim3 blk(256);
    auto cdiv = [](int a, int b) { return (a + b - 1) / b; };
    const int nbN = cdiv(N, 256);

    // ---- prep: zero counts + Wt builds + BN folds ----
    prep_kernel<<<nbN + 64 + 64 + 16 + 1, blk, 0, stream>>>(
        counts, N, nbN, W0, W1, sk1W, W2, sk2W, Wt0, Wt1, Wt2,
        b0v, bn0g, bn0b, bn0m, bn0v,
        b1v, bn1g, bn1b, bn1m, bn1v,
        b2v, bn2g, bn2b, bn2m, bn2v, bnS, bnO);

    // ---- layer-0 GEMM (with rank_hist fused as extra blocks) ----
    const int G0 = cdiv(N, 64);
    const int RB = cdiv(E, 1024);
    gemm0_rank_kernel<<<G0 + RB, blk, 0, stream>>>(x, Wt0, Hb, N, G0, dst, counts, rank, E);

    // ---- CSR finalize ----
    scan_block_kernel<<<nbN, blk, 0, stream>>>(counts, excl, bsum, N);
    scan_add_kernel<<<cdiv(N + 1, 256), blk, 0, stream>>>(excl, bsum, counts, rowptr, dinv, nbN, N, E);
    fill_csr_kernel<<<cdiv(E, 1024), blk, 0, stream>>>(src, dst, rank, rowptr, csr, E);

    // ---- layer 0 gather: residual = x (f32), out bf16 ----
    gather_bn_kernel<128, true, false, false><<<cdiv(N * 16, 256), blk, 0, stream>>>(
        rowptr, csr, Hb, dinv, bnS, bnO, x, Q0, nullptr, nullptr, nullptr, nullptr, N);

    // ---- layer 1: 128 -> 64, skip fused (bf16) ----
    mfma_gemm_kernel<128, 64, 64, true><<<cdiv(N, 64), blk, 0, stream>>>(
        nullptr, Q0, Wt1, sk1b, Hb, SKb, N);
    gather_bn_kernel<64, true, true, false><<<cdiv(N * 8, 256), blk, 0, stream>>>(
        rowptr, csr, Hb, dinv, bnS + 128, bnO + 128, SKb, P1,
        nullptr, nullptr, nullptr, nullptr, N);

    // ---- layer 2: 64 -> 32, skip fused (bf16), classifier fused ----
    mfma_gemm_kernel<64, 32, 32, true><<<cdiv(N, 128), blk, 0, stream>>>(
        nullptr, P1, Wt2, sk2b, Hb, SKb, N);
    gather_bn_kernel<32, false, true, true><<<cdiv(N * 4, 256), blk, 0, stream>>>(
        rowptr, csr, Hb, dinv, bnS + 192, bnO + 192, SKb, d_out, c1W, c1b, c2W, c2b, N);
}

// Round 9
// 173.209 us; speedup vs baseline: 1.0850x; 1.0483x over previous
//
#include <hip/hip_runtime.h>
#include <hip/hip_bf16.h>
#include <math.h>

// ---------------------------------------------------------------------------
// AdvancedGCN on MI355X — round 9:
//  * UNFUSE rank_hist from GEMM0 (r8 lesson: 48KB-LDS kernel starved the
//    atomic blocks to 12 waves/CU; LDS is per-kernel not per-block)
//  * rank_hist + Wt builds + BN fold combined into one ZERO-LDS kernel
//    (atomic blocks first; tiny transpose work hides under atomic latency)
// ---------------------------------------------------------------------------

#define BN_EPS 1e-5f

typedef __attribute__((ext_vector_type(8))) short bf16x8;
typedef __attribute__((ext_vector_type(4))) float f32x4;

static __device__ __forceinline__ float bf2f(unsigned int u16) {
    return __uint_as_float(u16 << 16);
}
static __device__ __forceinline__ unsigned short f2bf(float f) {
    unsigned int b = __float_as_uint(f);
    return (unsigned short)((b + 0x7FFFu + ((b >> 16) & 1u)) >> 16);
}
static __device__ __forceinline__ unsigned int pack2(float a, float b) {
    return (unsigned int)f2bf(a) | ((unsigned int)f2bf(b) << 16);
}
static __device__ __forceinline__ void unpack8(uint4 u, float* f) {
    f[0] = bf2f(u.x & 0xffffu); f[1] = bf2f(u.x >> 16);
    f[2] = bf2f(u.y & 0xffffu); f[3] = bf2f(u.y >> 16);
    f[4] = bf2f(u.z & 0xffffu); f[5] = bf2f(u.z >> 16);
    f[6] = bf2f(u.w & 0xffffu); f[7] = bf2f(u.w >> 16);
}
static __device__ __forceinline__ int swz(int row, int kb, int rowb) {
    return row * rowb + (kb ^ ((row & 7) << 4));
}

// --------------------------- zero counts -----------------------------------
__global__ void zero_counts_kernel(int* __restrict__ counts, int N) {
    int i = blockIdx.x * 256 + threadIdx.x;
    if (i < N) counts[i] = 0;
}

// ---------------- rank_hist + Wt builds + BN fold (ZERO LDS) ---------------
// blocks [0,RB): rank_hist | 64: Wt0 | 64: Wt1 | 16: Wt2 | 1: BN fold
__global__ void prep_rank_kernel(const int* __restrict__ dst, int* __restrict__ counts,
                                 int* __restrict__ rank, int E, int RB,
                                 const float* __restrict__ W0,
                                 const float* __restrict__ W1, const float* __restrict__ sk1W,
                                 const float* __restrict__ W2, const float* __restrict__ sk2W,
                                 unsigned short* __restrict__ Wt0,
                                 unsigned short* __restrict__ Wt1,
                                 unsigned short* __restrict__ Wt2,
                                 const float* __restrict__ b0v, const float* __restrict__ bn0g,
                                 const float* __restrict__ bn0b, const float* __restrict__ bn0m,
                                 const float* __restrict__ bn0v,
                                 const float* __restrict__ b1v, const float* __restrict__ bn1g,
                                 const float* __restrict__ bn1b, const float* __restrict__ bn1m,
                                 const float* __restrict__ bn1v,
                                 const float* __restrict__ b2v, const float* __restrict__ bn2g,
                                 const float* __restrict__ bn2b, const float* __restrict__ bn2m,
                                 const float* __restrict__ bn2v,
                                 float* __restrict__ bnS, float* __restrict__ bnO)
{
    int b = blockIdx.x, tid = threadIdx.x;
    if (b < RB) {
        int base = (b * 256 + tid) * 4;
        if (base + 3 < E) {
            int4 d = *(const int4*)(dst + base);
            int4 r;
            r.x = atomicAdd(&counts[d.x], 1);
            r.y = atomicAdd(&counts[d.y], 1);
            r.z = atomicAdd(&counts[d.z], 1);
            r.w = atomicAdd(&counts[d.w], 1);
            *(int4*)(rank + base) = r;
        } else {
            for (int e = base; e < E; ++e) rank[e] = atomicAdd(&counts[dst[e]], 1);
        }
        return;
    }
    b -= RB;
    if (b < 64) {                       // Wt0: M=128, K=128
        int idx = b * 256 + tid;
        int m = idx >> 7, k = idx & 127;
        Wt0[idx] = f2bf(W0[(size_t)k * 128 + m]);
        return;
    }
    b -= 64;
    if (b < 64) {                       // Wt1: M=64+64, K=128
        int idx = b * 256 + tid;
        int m = idx >> 7, k = idx & 127;
        float v = (m < 64) ? W1[(size_t)k * 64 + m] : sk1W[(size_t)k * 64 + (m - 64)];
        Wt1[idx] = f2bf(v);
        return;
    }
    b -= 64;
    if (b < 16) {                       // Wt2: M=32+32, K=64
        int idx = b * 256 + tid;
        int m = idx >> 6, k = idx & 63;
        float v = (m < 32) ? W2[(size_t)k * 32 + m] : sk2W[(size_t)k * 32 + (m - 32)];
        Wt2[idx] = f2bf(v);
        return;
    }
    // folded BN: bnS = g*rsqrt(v+eps); bnO = (bias - m)*bnS + b
    if (tid < 128) {
        float s = bn0g[tid] * rsqrtf(bn0v[tid] + BN_EPS);
        bnS[tid] = s;
        bnO[tid] = (b0v[tid] - bn0m[tid]) * s + bn0b[tid];
    } else if (tid < 192) {
        int c = tid - 128;
        float s = bn1g[c] * rsqrtf(bn1v[c] + BN_EPS);
        bnS[tid] = s;
        bnO[tid] = (b1v[c] - bn1m[c]) * s + bn1b[c];
    } else if (tid < 224) {
        int c = tid - 192;
        float s = bn2g[c] * rsqrtf(bn2v[c] + BN_EPS);
        bnS[tid] = s;
        bnO[tid] = (b2v[c] - bn2m[c]) * s + bn2b[c];
    }
}

// --------------------------- CSR build kernels -----------------------------
__global__ void scan_block_kernel(const int* __restrict__ counts, int* __restrict__ excl,
                                  int* __restrict__ bsum, int N) {
    __shared__ int s[256];
    int tid = threadIdx.x;
    int i = blockIdx.x * 256 + tid;
    int v = (i < N) ? counts[i] : 0;
    s[tid] = v;
    __syncthreads();
#pragma unroll
    for (int off = 1; off < 256; off <<= 1) {
        int t = (tid >= off) ? s[tid - off] : 0;
        __syncthreads();
        s[tid] += t;
        __syncthreads();
    }
    if (i < N) excl[i] = s[tid] - v;
    if (tid == 255) bsum[blockIdx.x] = s[255];
}

__global__ void scan_add_kernel(const int* __restrict__ excl, const int* __restrict__ bsum,
                                const int* __restrict__ counts,
                                int* __restrict__ rowptr, float* __restrict__ dinv,
                                int nb, int N, int E) {
    __shared__ int sb[256];
    int tid = threadIdx.x;
    int v = (tid < nb) ? bsum[tid] : 0;
    sb[tid] = v;
    __syncthreads();
#pragma unroll
    for (int off = 1; off < 256; off <<= 1) {
        int t = (tid >= off) ? sb[tid - off] : 0;
        __syncthreads();
        sb[tid] += t;
        __syncthreads();
    }
    int eb = sb[blockIdx.x] - ((blockIdx.x < nb) ? bsum[blockIdx.x] : 0);  // exclusive
    int i = blockIdx.x * 256 + tid;
    if (i < N) {
        rowptr[i] = excl[i] + eb;
        dinv[i]   = rsqrtf((float)counts[i] + 1.0f);
    }
    if (i == N) rowptr[N] = E;
}

__global__ void fill_csr_kernel(const int* __restrict__ src, const int* __restrict__ dst,
                                const int* __restrict__ rank, const int* __restrict__ rowptr,
                                int* __restrict__ csr, int E) {
    int base = (blockIdx.x * 256 + threadIdx.x) * 4;
    if (base + 3 < E) {
        int4 s = *(const int4*)(src + base);
        int4 d = *(const int4*)(dst + base);
        int4 r = *(const int4*)(rank + base);
        csr[rowptr[d.x] + r.x] = s.x;
        csr[rowptr[d.y] + r.y] = s.y;
        csr[rowptr[d.z] + r.z] = s.z;
        csr[rowptr[d.w] + r.w] = s.w;
    } else {
        for (int e = base; e < E; ++e) csr[rowptr[dst[e]] + rank[e]] = src[e];
    }
}

// ----------------------------- MFMA dual GEMM ------------------------------
// H(bf16)[N,M1] = X @ Wc ; SK(bf16)[N,M2] = X @ Wsk + skb (cols M1..M-1)
template <int K, int M1, int M2, bool IN_BF16>
__launch_bounds__(256)
__global__ void mfma_gemm_kernel(const float* __restrict__ Xf,
                                 const unsigned short* __restrict__ Xb,
                                 const unsigned short* __restrict__ Wt,
                                 const float* __restrict__ skb,
                                 unsigned short* __restrict__ H,
                                 unsigned short* __restrict__ SK, int N)
{
    constexpr int M    = M1 + M2;
    constexpr int BM   = 8192 / M;
    constexpr int WC   = M / 64;
    constexpr int ROWB = K * 2;
    constexpr int CPR  = K / 8;
    constexpr int WCH  = (M * K) / 2048;

    __shared__ unsigned char XsB[BM * K * 2];
    __shared__ unsigned char WsB[M * K * 2];

    const int tid = threadIdx.x;
    const int r0  = blockIdx.x * BM;

#pragma unroll
    for (int c = 0; c < 4; ++c) {           // BM*K/2048 == 4 for all layers
        int q   = tid + 256 * c;
        int row = q / CPR, kq = q % CPR;
        int grow = r0 + row;
        uint4 u = make_uint4(0u, 0u, 0u, 0u);
        if (IN_BF16) {
            if (grow < N) u = *(const uint4*)(Xb + (size_t)grow * K + kq * 8);
        } else {
            if (grow < N) {
                const float* p = Xf + (size_t)grow * K + kq * 8;
                float4 v0 = *(const float4*)p;
                float4 v1 = *(const float4*)(p + 4);
                u.x = pack2(v0.x, v0.y); u.y = pack2(v0.z, v0.w);
                u.z = pack2(v1.x, v1.y); u.w = pack2(v1.z, v1.w);
            }
        }
        *(uint4*)(XsB + swz(row, kq * 16, ROWB)) = u;
    }
#pragma unroll
    for (int c = 0; c < WCH; ++c) {
        int q = tid + 256 * c;
        int m = q / CPR, kq = q % CPR;
        uint4 u = *(const uint4*)(Wt + (size_t)m * K + kq * 8);
        *(uint4*)(WsB + swz(m, kq * 16, ROWB)) = u;
    }
    __syncthreads();

    const int lane = tid & 63, wid = tid >> 6;
    const int wr = wid / WC, wc = wid % WC;
    const int lrow = lane & 15;
    const int kb   = (lane >> 4) << 4;

    f32x4 acc[2][4];
#pragma unroll
    for (int fi = 0; fi < 2; ++fi)
#pragma unroll
        for (int fj = 0; fj < 4; ++fj)
            acc[fi][fj] = (f32x4){0.f, 0.f, 0.f, 0.f};

#pragma unroll
    for (int ks = 0; ks < K / 32; ++ks) {
        const int kb0 = ks * 64 + kb;
        bf16x8 a0 = *(const bf16x8*)(XsB + swz(wr * 32 +      lrow, kb0, ROWB));
        bf16x8 a1 = *(const bf16x8*)(XsB + swz(wr * 32 + 16 + lrow, kb0, ROWB));
        bf16x8 b0 = *(const bf16x8*)(WsB + swz(wc * 64 +      lrow, kb0, ROWB));
        bf16x8 b1 = *(const bf16x8*)(WsB + swz(wc * 64 + 16 + lrow, kb0, ROWB));
        bf16x8 b2 = *(const bf16x8*)(WsB + swz(wc * 64 + 32 + lrow, kb0, ROWB));
        bf16x8 b3 = *(const bf16x8*)(WsB + swz(wc * 64 + 48 + lrow, kb0, ROWB));
        acc[0][0] = __builtin_amdgcn_mfma_f32_16x16x32_bf16(a0, b0, acc[0][0], 0, 0, 0);
        acc[0][1] = __builtin_amdgcn_mfma_f32_16x16x32_bf16(a0, b1, acc[0][1], 0, 0, 0);
        acc[0][2] = __builtin_amdgcn_mfma_f32_16x16x32_bf16(a0, b2, acc[0][2], 0, 0, 0);
        acc[0][3] = __builtin_amdgcn_mfma_f32_16x16x32_bf16(a0, b3, acc[0][3], 0, 0, 0);
        acc[1][0] = __builtin_amdgcn_mfma_f32_16x16x32_bf16(a1, b0, acc[1][0], 0, 0, 0);
        acc[1][1] = __builtin_amdgcn_mfma_f32_16x16x32_bf16(a1, b1, acc[1][1], 0, 0, 0);
        acc[1][2] = __builtin_amdgcn_mfma_f32_16x16x32_bf16(a1, b2, acc[1][2], 0, 0, 0);
        acc[1][3] = __builtin_amdgcn_mfma_f32_16x16x32_bf16(a1, b3, acc[1][3], 0, 0, 0);
    }

    const int orow0 = r0 + wr * 32 + (lane >> 4) * 4;
#pragma unroll
    for (int fi = 0; fi < 2; ++fi) {
#pragma unroll
        for (int fj = 0; fj < 4; ++fj) {
            const int col = wc * 64 + fj * 16 + lrow;
            const bool conv = (M2 == 0) || (col < M1);
            const float sb = conv ? 0.f : skb[col - M1];
#pragma unroll
            for (int r = 0; r < 4; ++r) {
                const int row = orow0 + fi * 16 + r;
                if (row >= N) continue;
                const float val = acc[fi][fj][r];
                if (conv) H[(size_t)row * M1 + col] = f2bf(val);
                else      SK[(size_t)row * M2 + (col - M1)] = f2bf(val + sb);
            }
        }
    }
}

// ------------------ fused gather + self + BN + ReLU + residual -------------
// 8 channels (16B) per thread; optional fused classifier (M==32).
template <int M, bool OUT_BF16, bool RES_BF16, bool CLS>
__launch_bounds__(256)
__global__ void gather_bn_kernel(const int* __restrict__ rowptr, const int* __restrict__ csr,
                                 const unsigned short* __restrict__ H,
                                 const float* __restrict__ dinv,
                                 const float* __restrict__ bnS, const float* __restrict__ bnO,
                                 const void* __restrict__ res, void* __restrict__ out,
                                 const float* __restrict__ cW1, const float* __restrict__ cB1,
                                 const float* __restrict__ cW2, const float* __restrict__ cB2,
                                 int N)
{
    constexpr int TPN = M / 8;
    __shared__ float w1s[512];
    __shared__ float b1s[16];
    __shared__ float w2s[32];
    __shared__ float b2s[2];

    const int tid = threadIdx.x;
    if constexpr (CLS) {
        w1s[tid]       = cW1[tid];
        w1s[tid + 256] = cW1[tid + 256];
        if (tid < 16) b1s[tid] = cB1[tid];
        if (tid < 32) w2s[tid] = cW2[tid];
        if (tid < 2)  b2s[tid] = cB2[tid];
        __syncthreads();
    }

    int gid = blockIdx.x * 256 + tid;
    int n = gid / TPN;
    if (n >= N) return;
    const int c = (gid % TPN) * 8;

    float s[8], o[8];
    {
        float4 sa = *(const float4*)&bnS[c], sb_ = *(const float4*)&bnS[c + 4];
        float4 oa = *(const float4*)&bnO[c], ob_ = *(const float4*)&bnO[c + 4];
        s[0] = sa.x; s[1] = sa.y; s[2] = sa.z; s[3] = sa.w;
        s[4] = sb_.x; s[5] = sb_.y; s[6] = sb_.z; s[7] = sb_.w;
        o[0] = oa.x; o[1] = oa.y; o[2] = oa.z; o[3] = oa.w;
        o[4] = ob_.x; o[5] = ob_.y; o[6] = ob_.z; o[7] = ob_.w;
    }

    const float dn = dinv[n];
    float acc[8], hf[8];
    uint4 hs = *(const uint4*)&H[(size_t)n * M + c];
    unpack8(hs, hf);
    const float d2 = dn * dn;
#pragma unroll
    for (int k = 0; k < 8; ++k) acc[k] = hf[k] * d2;

    int p   = rowptr[n];
    int end = rowptr[n + 1];
    for (; p + 3 < end; p += 4) {
        int s0 = csr[p], s1 = csr[p + 1], s2 = csr[p + 2], s3 = csr[p + 3];
        uint4 h0 = *(const uint4*)&H[(size_t)s0 * M + c];
        uint4 h1 = *(const uint4*)&H[(size_t)s1 * M + c];
        uint4 h2 = *(const uint4*)&H[(size_t)s2 * M + c];
        uint4 h3 = *(const uint4*)&H[(size_t)s3 * M + c];
        float w0 = dinv[s0] * dn, w1 = dinv[s1] * dn;
        float w2 = dinv[s2] * dn, w3 = dinv[s3] * dn;
        float f0[8], f1[8], f2[8], f3[8];
        unpack8(h0, f0); unpack8(h1, f1); unpack8(h2, f2); unpack8(h3, f3);
#pragma unroll
        for (int k = 0; k < 8; ++k) acc[k] = fmaf(f0[k], w0, acc[k]);
#pragma unroll
        for (int k = 0; k < 8; ++k) acc[k] = fmaf(f1[k], w1, acc[k]);
#pragma unroll
        for (int k = 0; k < 8; ++k) acc[k] = fmaf(f2[k], w2, acc[k]);
#pragma unroll
        for (int k = 0; k < 8; ++k) acc[k] = fmaf(f3[k], w3, acc[k]);
    }
    for (; p < end; ++p) {
        int s0 = csr[p];
        uint4 h0 = *(const uint4*)&H[(size_t)s0 * M + c];
        float w0 = dinv[s0] * dn;
        float f0[8];
        unpack8(h0, f0);
#pragma unroll
        for (int k = 0; k < 8; ++k) acc[k] = fmaf(f0[k], w0, acc[k]);
    }

    // residual
    float rr[8];
    if constexpr (RES_BF16) {
        const unsigned short* rp = (const unsigned short*)res;
        uint4 r0 = *(const uint4*)&rp[(size_t)n * M + c];
        unpack8(r0, rr);
    } else {
        const float* rp = (const float*)res;
        float4 r0 = *(const float4*)&rp[(size_t)n * M + c];
        float4 r1 = *(const float4*)&rp[(size_t)n * M + c + 4];
        rr[0] = r0.x; rr[1] = r0.y; rr[2] = r0.z; rr[3] = r0.w;
        rr[4] = r1.x; rr[5] = r1.y; rr[6] = r1.z; rr[7] = r1.w;
    }

    float outv[8];
#pragma unroll
    for (int k = 0; k < 8; ++k)
        outv[k] = fmaxf(fmaf(acc[k], s[k], o[k]), 0.f) + rr[k];

    if constexpr (CLS) {
        // partial 32->16 MLP over this thread's 8 channels; 4-lane reduce
        float h[16];
#pragma unroll
        for (int j = 0; j < 16; ++j) h[j] = 0.f;
#pragma unroll
        for (int k = 0; k < 8; ++k)
#pragma unroll
            for (int j = 0; j < 16; ++j)
                h[j] = fmaf(outv[k], w1s[(c + k) * 16 + j], h[j]);
#pragma unroll
        for (int j = 0; j < 16; ++j) {
            h[j] += __shfl_xor(h[j], 1);
            h[j] += __shfl_xor(h[j], 2);
        }
        float z0 = b2s[0], z1 = b2s[1];
#pragma unroll
        for (int j = 0; j < 16; ++j) {
            float r = fmaxf(h[j] + b1s[j], 0.f);
            z0 = fmaf(r, w2s[j * 2 + 0], z0);
            z1 = fmaf(r, w2s[j * 2 + 1], z1);
        }
        if ((tid & 3) == 0) {
            float mx  = fmaxf(z0, z1);
            float lse = mx + logf(expf(z0 - mx) + expf(z1 - mx));
            float* op = (float*)out;
            op[(size_t)n * 2 + 0] = z0 - lse;
            op[(size_t)n * 2 + 1] = z1 - lse;
        }
    } else if constexpr (OUT_BF16) {
        unsigned short* op = (unsigned short*)out;
        uint4 u;
        u.x = pack2(outv[0], outv[1]); u.y = pack2(outv[2], outv[3]);
        u.z = pack2(outv[4], outv[5]); u.w = pack2(outv[6], outv[7]);
        *(uint4*)&op[(size_t)n * M + c] = u;
    } else {
        float* op = (float*)out;
        *(float4*)&op[(size_t)n * M + c]     = make_float4(outv[0], outv[1], outv[2], outv[3]);
        *(float4*)&op[(size_t)n * M + c + 4] = make_float4(outv[4], outv[5], outv[6], outv[7]);
    }
}

// ------------------------------- launch ------------------------------------
extern "C" void kernel_launch(void* const* d_in, const int* in_sizes, int n_in,
                              void* d_out, int out_size, void* d_ws, size_t ws_size,
                              hipStream_t stream)
{
    const float* x    = (const float*)d_in[0];
    const int*   edge = (const int*)d_in[1];
    const float* W0   = (const float*)d_in[2];
    const float* b0v  = (const float*)d_in[3];
    const float* bn0g = (const float*)d_in[4];
    const float* bn0b = (const float*)d_in[5];
    const float* bn0m = (const float*)d_in[6];
    const float* bn0v = (const float*)d_in[7];
    const float* W1   = (const float*)d_in[8];
    const float* b1v  = (const float*)d_in[9];
    const float* bn1g = (const float*)d_in[10];
    const float* bn1b = (const float*)d_in[11];
    const float* bn1m = (const float*)d_in[12];
    const float* bn1v = (const float*)d_in[13];
    const float* sk1W = (const float*)d_in[14];
    const float* sk1b = (const float*)d_in[15];
    const float* W2   = (const float*)d_in[16];
    const float* b2v  = (const float*)d_in[17];
    const float* bn2g = (const float*)d_in[18];
    const float* bn2b = (const float*)d_in[19];
    const float* bn2m = (const float*)d_in[20];
    const float* bn2v = (const float*)d_in[21];
    const float* sk2W = (const float*)d_in[22];
    const float* sk2b = (const float*)d_in[23];
    const float* c1W  = (const float*)d_in[24];
    const float* c1b  = (const float*)d_in[25];
    const float* c2W  = (const float*)d_in[26];
    const float* c2b  = (const float*)d_in[27];

    const int N = in_sizes[0] / 128;
    const int E = in_sizes[1] / 2;
    const int* src = edge;
    const int* dst = edge + E;

    char*  ws  = (char*)d_ws;
    size_t off = 0;
    auto alloc = [&](size_t bytes) -> char* {
        char* p = ws + off;
        off += (bytes + 255) & ~(size_t)255;
        return p;
    };
    float*          dinv   = (float*)alloc((size_t)N * 4);
    int*            counts = (int*)  alloc((size_t)N * 4);
    int*            excl   = (int*)  alloc((size_t)N * 4);
    int*            rowptr = (int*)  alloc((size_t)(N + 1) * 4);
    int*            bsum   = (int*)  alloc(256 * 4);
    int*            rank   = (int*)  alloc((size_t)E * 4);
    int*            csr    = (int*)  alloc((size_t)E * 4);
    unsigned short* Hb     = (unsigned short*)alloc((size_t)N * 128 * 2);
    unsigned short* SKb    = (unsigned short*)alloc((size_t)N * 64 * 2);
    unsigned short* Q0     = (unsigned short*)alloc((size_t)N * 128 * 2);
    unsigned short* P1     = (unsigned short*)alloc((size_t)N * 64 * 2);
    unsigned short* Wt0    = (unsigned short*)alloc(128 * 128 * 2);
    unsigned short* Wt1    = (unsigned short*)alloc(128 * 128 * 2);
    unsigned short* Wt2    = (unsigned short*)alloc(64 * 64 * 2);
    float*          bnS    = (float*)alloc(224 * 4);
    float*          bnO    = (float*)alloc(224 * 4);
    (void)ws_size; (void)n_in; (void)out_size;

    dim3 blk(256);
    auto cdiv = [](int a, int b) { return (a + b - 1) / b; };
    const int nbN = cdiv(N, 256);
    const int RB  = cdiv(E, 1024);

    // ---- zero counts, then rank_hist + Wt builds + BN fold (zero-LDS) ----
    zero_counts_kernel<<<nbN, blk, 0, stream>>>(counts, N);
    prep_rank_kernel<<<RB + 64 + 64 + 16 + 1, blk, 0, stream>>>(
        dst, counts, rank, E, RB, W0, W1, sk1W, W2, sk2W, Wt0, Wt1, Wt2,
        b0v, bn0g, bn0b, bn0m, bn0v,
        b1v, bn1g, bn1b, bn1m, bn1v,
        b2v, bn2g, bn2b, bn2m, bn2v, bnS, bnO);

    // ---- layer-0 GEMM (plain; 48KB LDS confined to this kernel) ----
    mfma_gemm_kernel<128, 128, 0, false><<<cdiv(N, 64), blk, 0, stream>>>(
        x, nullptr, Wt0, nullptr, Hb, nullptr, N);

    // ---- CSR finalize ----
    scan_block_kernel<<<nbN, blk, 0, stream>>>(counts, excl, bsum, N);
    scan_add_kernel<<<cdiv(N + 1, 256), blk, 0, stream>>>(excl, bsum, counts, rowptr, dinv, nbN, N, E);
    fill_csr_kernel<<<cdiv(E, 1024), blk, 0, stream>>>(src, dst, rank, rowptr, csr, E);

    // ---- layer 0 gather: residual = x (f32), out bf16 ----
    gather_bn_kernel<128, true, false, false><<<cdiv(N * 16, 256), blk, 0, stream>>>(
        rowptr, csr, Hb, dinv, bnS, bnO, x, Q0, nullptr, nullptr, nullptr, nullptr, N);

    // ---- layer 1: 128 -> 64, skip fused (bf16) ----
    mfma_gemm_kernel<128, 64, 64, true><<<cdiv(N, 64), blk, 0, stream>>>(
        nullptr, Q0, Wt1, sk1b, Hb, SKb, N);
    gather_bn_kernel<64, true, true, false><<<cdiv(N * 8, 256), blk, 0, stream>>>(
        rowptr, csr, Hb, dinv, bnS + 128, bnO + 128, SKb, P1,
        nullptr, nullptr, nullptr, nullptr, N);

    // ---- layer 2: 64 -> 32, skip fused (bf16), classifier fused ----
    mfma_gemm_kernel<64, 32, 32, true><<<cdiv(N, 128), blk, 0, stream>>>(
        nullptr, P1, Wt2, sk2b, Hb, SKb, N);
    gather_bn_kernel<32, false, true, true><<<cdiv(N * 4, 256), blk, 0, stream>>>(
        rowptr, csr, Hb, dinv, bnS + 192, bnO + 192, SKb, d_out, c1W, c1b, c2W, c2b, N);
}

// Round 10
// 170.283 us; speedup vs baseline: 1.1037x; 1.0172x over previous
//
#include <hip/hip_runtime.h>
#include <hip/hip_bf16.h>
#include <math.h>

// ---------------------------------------------------------------------------
// AdvancedGCN on MI355X — round 10:
//  * 13 -> 10 dispatches:
//    - init_kernel: zero_counts + Wt builds + BN fold (zero-LDS)
//    - rank_kernel: pure rank_hist
//    - gemm0_scan_kernel: GEMM0 blocks + scan_block tail blocks (196 blocks,
//      LDS-aliased; safe unlike r8 because tail work is tiny and <=1 block/CU)
// ---------------------------------------------------------------------------

#define BN_EPS 1e-5f

typedef __attribute__((ext_vector_type(8))) short bf16x8;
typedef __attribute__((ext_vector_type(4))) float f32x4;

static __device__ __forceinline__ float bf2f(unsigned int u16) {
    return __uint_as_float(u16 << 16);
}
static __device__ __forceinline__ unsigned short f2bf(float f) {
    unsigned int b = __float_as_uint(f);
    return (unsigned short)((b + 0x7FFFu + ((b >> 16) & 1u)) >> 16);
}
static __device__ __forceinline__ unsigned int pack2(float a, float b) {
    return (unsigned int)f2bf(a) | ((unsigned int)f2bf(b) << 16);
}
static __device__ __forceinline__ void unpack8(uint4 u, float* f) {
    f[0] = bf2f(u.x & 0xffffu); f[1] = bf2f(u.x >> 16);
    f[2] = bf2f(u.y & 0xffffu); f[3] = bf2f(u.y >> 16);
    f[4] = bf2f(u.z & 0xffffu); f[5] = bf2f(u.z >> 16);
    f[6] = bf2f(u.w & 0xffffu); f[7] = bf2f(u.w >> 16);
}
static __device__ __forceinline__ int swz(int row, int kb, int rowb) {
    return row * rowb + (kb ^ ((row & 7) << 4));
}

// ---------------- init: zero counts + Wt builds + BN fold (ZERO LDS) -------
// blocks [0,nbZero): zero | 64: Wt0 | 64: Wt1 | 16: Wt2 | 1: BN fold
__global__ void init_kernel(int* __restrict__ counts, int N, int nbZero,
                            const float* __restrict__ W0,
                            const float* __restrict__ W1, const float* __restrict__ sk1W,
                            const float* __restrict__ W2, const float* __restrict__ sk2W,
                            unsigned short* __restrict__ Wt0,
                            unsigned short* __restrict__ Wt1,
                            unsigned short* __restrict__ Wt2,
                            const float* __restrict__ b0v, const float* __restrict__ bn0g,
                            const float* __restrict__ bn0b, const float* __restrict__ bn0m,
                            const float* __restrict__ bn0v,
                            const float* __restrict__ b1v, const float* __restrict__ bn1g,
                            const float* __restrict__ bn1b, const float* __restrict__ bn1m,
                            const float* __restrict__ bn1v,
                            const float* __restrict__ b2v, const float* __restrict__ bn2g,
                            const float* __restrict__ bn2b, const float* __restrict__ bn2m,
                            const float* __restrict__ bn2v,
                            float* __restrict__ bnS, float* __restrict__ bnO)
{
    int b = blockIdx.x, tid = threadIdx.x;
    if (b < nbZero) {
        int i = b * 256 + tid;
        if (i < N) counts[i] = 0;
        return;
    }
    b -= nbZero;
    if (b < 64) {                       // Wt0: M=128, K=128
        int idx = b * 256 + tid;
        int m = idx >> 7, k = idx & 127;
        Wt0[idx] = f2bf(W0[(size_t)k * 128 + m]);
        return;
    }
    b -= 64;
    if (b < 64) {                       // Wt1: M=64+64, K=128
        int idx = b * 256 + tid;
        int m = idx >> 7, k = idx & 127;
        float v = (m < 64) ? W1[(size_t)k * 64 + m] : sk1W[(size_t)k * 64 + (m - 64)];
        Wt1[idx] = f2bf(v);
        return;
    }
    b -= 64;
    if (b < 16) {                       // Wt2: M=32+32, K=64
        int idx = b * 256 + tid;
        int m = idx >> 6, k = idx & 63;
        float v = (m < 32) ? W2[(size_t)k * 32 + m] : sk2W[(size_t)k * 32 + (m - 32)];
        Wt2[idx] = f2bf(v);
        return;
    }
    // folded BN: bnS = g*rsqrt(v+eps); bnO = (bias - m)*bnS + b
    if (tid < 128) {
        float s = bn0g[tid] * rsqrtf(bn0v[tid] + BN_EPS);
        bnS[tid] = s;
        bnO[tid] = (b0v[tid] - bn0m[tid]) * s + bn0b[tid];
    } else if (tid < 192) {
        int c = tid - 128;
        float s = bn1g[c] * rsqrtf(bn1v[c] + BN_EPS);
        bnS[tid] = s;
        bnO[tid] = (b1v[c] - bn1m[c]) * s + bn1b[c];
    } else if (tid < 224) {
        int c = tid - 192;
        float s = bn2g[c] * rsqrtf(bn2v[c] + BN_EPS);
        bnS[tid] = s;
        bnO[tid] = (b2v[c] - bn2m[c]) * s + bn2b[c];
    }
}

// ------------------------------ rank hist ----------------------------------
__global__ void rank_kernel(const int* __restrict__ dst, int* __restrict__ counts,
                            int* __restrict__ rank, int E) {
    int base = (blockIdx.x * 256 + threadIdx.x) * 4;
    if (base + 3 < E) {
        int4 d = *(const int4*)(dst + base);
        int4 r;
        r.x = atomicAdd(&counts[d.x], 1);
        r.y = atomicAdd(&counts[d.y], 1);
        r.z = atomicAdd(&counts[d.z], 1);
        r.w = atomicAdd(&counts[d.w], 1);
        *(int4*)(rank + base) = r;
    } else {
        for (int e = base; e < E; ++e) rank[e] = atomicAdd(&counts[dst[e]], 1);
    }
}

// --------------------------- MFMA GEMM body --------------------------------
// H(bf16)[N,M1] = X @ Wc ; SK(bf16)[N,M2] = X @ Wsk + skb (cols M1..M-1)
template <int K, int M1, int M2, bool IN_BF16>
static __device__ __forceinline__ void gemm_body(
    const float* __restrict__ Xf, const unsigned short* __restrict__ Xb,
    const unsigned short* __restrict__ Wt, const float* __restrict__ skb,
    unsigned short* __restrict__ H, unsigned short* __restrict__ SK, int N,
    unsigned char* XsB, unsigned char* WsB, int bid)
{
    constexpr int M    = M1 + M2;
    constexpr int BM   = 8192 / M;
    constexpr int WC   = M / 64;
    constexpr int ROWB = K * 2;
    constexpr int CPR  = K / 8;
    constexpr int WCH  = (M * K) / 2048;

    const int tid = threadIdx.x;
    const int r0  = bid * BM;

#pragma unroll
    for (int c = 0; c < 4; ++c) {           // BM*K/2048 == 4 for all layers
        int q   = tid + 256 * c;
        int row = q / CPR, kq = q % CPR;
        int grow = r0 + row;
        uint4 u = make_uint4(0u, 0u, 0u, 0u);
        if (IN_BF16) {
            if (grow < N) u = *(const uint4*)(Xb + (size_t)grow * K + kq * 8);
        } else {
            if (grow < N) {
                const float* p = Xf + (size_t)grow * K + kq * 8;
                float4 v0 = *(const float4*)p;
                float4 v1 = *(const float4*)(p + 4);
                u.x = pack2(v0.x, v0.y); u.y = pack2(v0.z, v0.w);
                u.z = pack2(v1.x, v1.y); u.w = pack2(v1.z, v1.w);
            }
        }
        *(uint4*)(XsB + swz(row, kq * 16, ROWB)) = u;
    }
#pragma unroll
    for (int c = 0; c < WCH; ++c) {
        int q = tid + 256 * c;
        int m = q / CPR, kq = q % CPR;
        uint4 u = *(const uint4*)(Wt + (size_t)m * K + kq * 8);
        *(uint4*)(WsB + swz(m, kq * 16, ROWB)) = u;
    }
    __syncthreads();

    const int lane = tid & 63, wid = tid >> 6;
    const int wr = wid / WC, wc = wid % WC;
    const int lrow = lane & 15;
    const int kb   = (lane >> 4) << 4;

    f32x4 acc[2][4];
#pragma unroll
    for (int fi = 0; fi < 2; ++fi)
#pragma unroll
        for (int fj = 0; fj < 4; ++fj)
            acc[fi][fj] = (f32x4){0.f, 0.f, 0.f, 0.f};

#pragma unroll
    for (int ks = 0; ks < K / 32; ++ks) {
        const int kb0 = ks * 64 + kb;
        bf16x8 a0 = *(const bf16x8*)(XsB + swz(wr * 32 +      lrow, kb0, ROWB));
        bf16x8 a1 = *(const bf16x8*)(XsB + swz(wr * 32 + 16 + lrow, kb0, ROWB));
        bf16x8 b0 = *(const bf16x8*)(WsB + swz(wc * 64 +      lrow, kb0, ROWB));
        bf16x8 b1 = *(const bf16x8*)(WsB + swz(wc * 64 + 16 + lrow, kb0, ROWB));
        bf16x8 b2 = *(const bf16x8*)(WsB + swz(wc * 64 + 32 + lrow, kb0, ROWB));
        bf16x8 b3 = *(const bf16x8*)(WsB + swz(wc * 64 + 48 + lrow, kb0, ROWB));
        acc[0][0] = __builtin_amdgcn_mfma_f32_16x16x32_bf16(a0, b0, acc[0][0], 0, 0, 0);
        acc[0][1] = __builtin_amdgcn_mfma_f32_16x16x32_bf16(a0, b1, acc[0][1], 0, 0, 0);
        acc[0][2] = __builtin_amdgcn_mfma_f32_16x16x32_bf16(a0, b2, acc[0][2], 0, 0, 0);
        acc[0][3] = __builtin_amdgcn_mfma_f32_16x16x32_bf16(a0, b3, acc[0][3], 0, 0, 0);
        acc[1][0] = __builtin_amdgcn_mfma_f32_16x16x32_bf16(a1, b0, acc[1][0], 0, 0, 0);
        acc[1][1] = __builtin_amdgcn_mfma_f32_16x16x32_bf16(a1, b1, acc[1][1], 0, 0, 0);
        acc[1][2] = __builtin_amdgcn_mfma_f32_16x16x32_bf16(a1, b2, acc[1][2], 0, 0, 0);
        acc[1][3] = __builtin_amdgcn_mfma_f32_16x16x32_bf16(a1, b3, acc[1][3], 0, 0, 0);
    }

    const int orow0 = r0 + wr * 32 + (lane >> 4) * 4;
#pragma unroll
    for (int fi = 0; fi < 2; ++fi) {
#pragma unroll
        for (int fj = 0; fj < 4; ++fj) {
            const int col = wc * 64 + fj * 16 + lrow;
            const bool conv = (M2 == 0) || (col < M1);
            const float sb = conv ? 0.f : skb[col - M1];
#pragma unroll
            for (int r = 0; r < 4; ++r) {
                const int row = orow0 + fi * 16 + r;
                if (row >= N) continue;
                const float val = acc[fi][fj][r];
                if (conv) H[(size_t)row * M1 + col] = f2bf(val);
                else      SK[(size_t)row * M2 + (col - M1)] = f2bf(val + sb);
            }
        }
    }
}

// plain GEMM kernels (layers 1,2)
template <int K, int M1, int M2, bool IN_BF16>
__launch_bounds__(256)
__global__ void mfma_gemm_kernel(const float* __restrict__ Xf,
                                 const unsigned short* __restrict__ Xb,
                                 const unsigned short* __restrict__ Wt,
                                 const float* __restrict__ skb,
                                 unsigned short* __restrict__ H,
                                 unsigned short* __restrict__ SK, int N)
{
    constexpr int M  = M1 + M2;
    constexpr int BM = 8192 / M;
    __shared__ unsigned char XsB[BM * K * 2];
    __shared__ unsigned char WsB[M * K * 2];
    gemm_body<K, M1, M2, IN_BF16>(Xf, Xb, Wt, skb, H, SK, N, XsB, WsB, blockIdx.x);
}

// GEMM0 + scan_block tail (196 tiny blocks, LDS aliased onto GEMM's buffers)
__launch_bounds__(256)
__global__ void gemm0_scan_kernel(const float* __restrict__ X,
                                  const unsigned short* __restrict__ Wt,
                                  unsigned short* __restrict__ H, int N, int G0,
                                  const int* __restrict__ counts,
                                  int* __restrict__ excl, int* __restrict__ bsum)
{
    __shared__ unsigned char XsB[64 * 128 * 2];
    __shared__ unsigned char WsB[128 * 128 * 2];
    if (blockIdx.x < G0) {
        gemm_body<128, 128, 0, false>(X, nullptr, Wt, nullptr, H, nullptr, N,
                                      XsB, WsB, blockIdx.x);
        return;
    }
    // scan_block over counts (counts final: rank_kernel completed)
    int* s = (int*)XsB;
    const int sbid = blockIdx.x - G0;
    const int tid  = threadIdx.x;
    const int i    = sbid * 256 + tid;
    int v = (i < N) ? counts[i] : 0;
    s[tid] = v;
    __syncthreads();
#pragma unroll
    for (int off = 1; off < 256; off <<= 1) {
        int t = (tid >= off) ? s[tid - off] : 0;
        __syncthreads();
        s[tid] += t;
        __syncthreads();
    }
    if (i < N) excl[i] = s[tid] - v;
    if (tid == 255) bsum[sbid] = s[255];
}

// --------------------------- CSR finalize ----------------------------------
__global__ void scan_add_kernel(const int* __restrict__ excl, const int* __restrict__ bsum,
                                const int* __restrict__ counts,
                                int* __restrict__ rowptr, float* __restrict__ dinv,
                                int nb, int N, int E) {
    __shared__ int sb[256];
    int tid = threadIdx.x;
    int v = (tid < nb) ? bsum[tid] : 0;
    sb[tid] = v;
    __syncthreads();
#pragma unroll
    for (int off = 1; off < 256; off <<= 1) {
        int t = (tid >= off) ? sb[tid - off] : 0;
        __syncthreads();
        sb[tid] += t;
        __syncthreads();
    }
    int eb = sb[blockIdx.x] - ((blockIdx.x < nb) ? bsum[blockIdx.x] : 0);  // exclusive
    int i = blockIdx.x * 256 + tid;
    if (i < N) {
        rowptr[i] = excl[i] + eb;
        dinv[i]   = rsqrtf((float)counts[i] + 1.0f);
    }
    if (i == N) rowptr[N] = E;
}

__global__ void fill_csr_kernel(const int* __restrict__ src, const int* __restrict__ dst,
                                const int* __restrict__ rank, const int* __restrict__ rowptr,
                                int* __restrict__ csr, int E) {
    int base = (blockIdx.x * 256 + threadIdx.x) * 4;
    if (base + 3 < E) {
        int4 s = *(const int4*)(src + base);
        int4 d = *(const int4*)(dst + base);
        int4 r = *(const int4*)(rank + base);
        csr[rowptr[d.x] + r.x] = s.x;
        csr[rowptr[d.y] + r.y] = s.y;
        csr[rowptr[d.z] + r.z] = s.z;
        csr[rowptr[d.w] + r.w] = s.w;
    } else {
        for (int e = base; e < E; ++e) csr[rowptr[dst[e]] + rank[e]] = src[e];
    }
}

// ------------------ fused gather + self + BN + ReLU + residual -------------
// 8 channels (16B) per thread; optional fused classifier (M==32).
template <int M, bool OUT_BF16, bool RES_BF16, bool CLS>
__launch_bounds__(256)
__global__ void gather_bn_kernel(const int* __restrict__ rowptr, const int* __restrict__ csr,
                                 const unsigned short* __restrict__ H,
                                 const float* __restrict__ dinv,
                                 const float* __restrict__ bnS, const float* __restrict__ bnO,
                                 const void* __restrict__ res, void* __restrict__ out,
                                 const float* __restrict__ cW1, const float* __restrict__ cB1,
                                 const float* __restrict__ cW2, const float* __restrict__ cB2,
                                 int N)
{
    constexpr int TPN = M / 8;
    __shared__ float w1s[512];
    __shared__ float b1s[16];
    __shared__ float w2s[32];
    __shared__ float b2s[2];

    const int tid = threadIdx.x;
    if constexpr (CLS) {
        w1s[tid]       = cW1[tid];
        w1s[tid + 256] = cW1[tid + 256];
        if (tid < 16) b1s[tid] = cB1[tid];
        if (tid < 32) w2s[tid] = cW2[tid];
        if (tid < 2)  b2s[tid] = cB2[tid];
        __syncthreads();
    }

    int gid = blockIdx.x * 256 + tid;
    int n = gid / TPN;
    if (n >= N) return;
    const int c = (gid % TPN) * 8;

    float s[8], o[8];
    {
        float4 sa = *(const float4*)&bnS[c], sb_ = *(const float4*)&bnS[c + 4];
        float4 oa = *(const float4*)&bnO[c], ob_ = *(const float4*)&bnO[c + 4];
        s[0] = sa.x; s[1] = sa.y; s[2] = sa.z; s[3] = sa.w;
        s[4] = sb_.x; s[5] = sb_.y; s[6] = sb_.z; s[7] = sb_.w;
        o[0] = oa.x; o[1] = oa.y; o[2] = oa.z; o[3] = oa.w;
        o[4] = ob_.x; o[5] = ob_.y; o[6] = ob_.z; o[7] = ob_.w;
    }

    const float dn = dinv[n];
    float acc[8], hf[8];
    uint4 hs = *(const uint4*)&H[(size_t)n * M + c];
    unpack8(hs, hf);
    const float d2 = dn * dn;
#pragma unroll
    for (int k = 0; k < 8; ++k) acc[k] = hf[k] * d2;

    int p   = rowptr[n];
    int end = rowptr[n + 1];
    for (; p + 3 < end; p += 4) {
        int s0 = csr[p], s1 = csr[p + 1], s2 = csr[p + 2], s3 = csr[p + 3];
        uint4 h0 = *(const uint4*)&H[(size_t)s0 * M + c];
        uint4 h1 = *(const uint4*)&H[(size_t)s1 * M + c];
        uint4 h2 = *(const uint4*)&H[(size_t)s2 * M + c];
        uint4 h3 = *(const uint4*)&H[(size_t)s3 * M + c];
        float w0 = dinv[s0] * dn, w1 = dinv[s1] * dn;
        float w2 = dinv[s2] * dn, w3 = dinv[s3] * dn;
        float f0[8], f1[8], f2[8], f3[8];
        unpack8(h0, f0); unpack8(h1, f1); unpack8(h2, f2); unpack8(h3, f3);
#pragma unroll
        for (int k = 0; k < 8; ++k) acc[k] = fmaf(f0[k], w0, acc[k]);
#pragma unroll
        for (int k = 0; k < 8; ++k) acc[k] = fmaf(f1[k], w1, acc[k]);
#pragma unroll
        for (int k = 0; k < 8; ++k) acc[k] = fmaf(f2[k], w2, acc[k]);
#pragma unroll
        for (int k = 0; k < 8; ++k) acc[k] = fmaf(f3[k], w3, acc[k]);
    }
    for (; p < end; ++p) {
        int s0 = csr[p];
        uint4 h0 = *(const uint4*)&H[(size_t)s0 * M + c];
        float w0 = dinv[s0] * dn;
        float f0[8];
        unpack8(h0, f0);
#pragma unroll
        for (int k = 0; k < 8; ++k) acc[k] = fmaf(f0[k], w0, acc[k]);
    }

    // residual
    float rr[8];
    if constexpr (RES_BF16) {
        const unsigned short* rp = (const unsigned short*)res;
        uint4 r0 = *(const uint4*)&rp[(size_t)n * M + c];
        unpack8(r0, rr);
    } else {
        const float* rp = (const float*)res;
        float4 r0 = *(const float4*)&rp[(size_t)n * M + c];
        float4 r1 = *(const float4*)&rp[(size_t)n * M + c + 4];
        rr[0] = r0.x; rr[1] = r0.y; rr[2] = r0.z; rr[3] = r0.w;
        rr[4] = r1.x; rr[5] = r1.y; rr[6] = r1.z; rr[7] = r1.w;
    }

    float outv[8];
#pragma unroll
    for (int k = 0; k < 8; ++k)
        outv[k] = fmaxf(fmaf(acc[k], s[k], o[k]), 0.f) + rr[k];

    if constexpr (CLS) {
        // partial 32->16 MLP over this thread's 8 channels; 4-lane reduce
        float h[16];
#pragma unroll
        for (int j = 0; j < 16; ++j) h[j] = 0.f;
#pragma unroll
        for (int k = 0; k < 8; ++k)
#pragma unroll
            for (int j = 0; j < 16; ++j)
                h[j] = fmaf(outv[k], w1s[(c + k) * 16 + j], h[j]);
#pragma unroll
        for (int j = 0; j < 16; ++j) {
            h[j] += __shfl_xor(h[j], 1);
            h[j] += __shfl_xor(h[j], 2);
        }
        float z0 = b2s[0], z1 = b2s[1];
#pragma unroll
        for (int j = 0; j < 16; ++j) {
            float r = fmaxf(h[j] + b1s[j], 0.f);
            z0 = fmaf(r, w2s[j * 2 + 0], z0);
            z1 = fmaf(r, w2s[j * 2 + 1], z1);
        }
        if ((tid & 3) == 0) {
            float mx  = fmaxf(z0, z1);
            float lse = mx + logf(expf(z0 - mx) + expf(z1 - mx));
            float* op = (float*)out;
            op[(size_t)n * 2 + 0] = z0 - lse;
            op[(size_t)n * 2 + 1] = z1 - lse;
        }
    } else if constexpr (OUT_BF16) {
        unsigned short* op = (unsigned short*)out;
        uint4 u;
        u.x = pack2(outv[0], outv[1]); u.y = pack2(outv[2], outv[3]);
        u.z = pack2(outv[4], outv[5]); u.w = pack2(outv[6], outv[7]);
        *(uint4*)&op[(size_t)n * M + c] = u;
    } else {
        float* op = (float*)out;
        *(float4*)&op[(size_t)n * M + c]     = make_float4(outv[0], outv[1], outv[2], outv[3]);
        *(float4*)&op[(size_t)n * M + c + 4] = make_float4(outv[4], outv[5], outv[6], outv[7]);
    }
}

// ------------------------------- launch ------------------------------------
extern "C" void kernel_launch(void* const* d_in, const int* in_sizes, int n_in,
                              void* d_out, int out_size, void* d_ws, size_t ws_size,
                              hipStream_t stream)
{
    const float* x    = (const float*)d_in[0];
    const int*   edge = (const int*)d_in[1];
    const float* W0   = (const float*)d_in[2];
    const float* b0v  = (const float*)d_in[3];
    const float* bn0g = (const float*)d_in[4];
    const float* bn0b = (const float*)d_in[5];
    const float* bn0m = (const float*)d_in[6];
    const float* bn0v = (const float*)d_in[7];
    const float* W1   = (const float*)d_in[8];
    const float* b1v  = (const float*)d_in[9];
    const float* bn1g = (const float*)d_in[10];
    const float* bn1b = (const float*)d_in[11];
    const float* bn1m = (const float*)d_in[12];
    const float* bn1v = (const float*)d_in[13];
    const float* sk1W = (const float*)d_in[14];
    const float* sk1b = (const float*)d_in[15];
    const float* W2   = (const float*)d_in[16];
    const float* b2v  = (const float*)d_in[17];
    const float* bn2g = (const float*)d_in[18];
    const float* bn2b = (const float*)d_in[19];
    const float* bn2m = (const float*)d_in[20];
    const float* bn2v = (const float*)d_in[21];
    const float* sk2W = (const float*)d_in[22];
    const float* sk2b = (const float*)d_in[23];
    const float* c1W  = (const float*)d_in[24];
    const float* c1b  = (const float*)d_in[25];
    const float* c2W  = (const float*)d_in[26];
    const float* c2b  = (const float*)d_in[27];

    const int N = in_sizes[0] / 128;
    const int E = in_sizes[1] / 2;
    const int* src = edge;
    const int* dst = edge + E;

    char*  ws  = (char*)d_ws;
    size_t off = 0;
    auto alloc = [&](size_t bytes) -> char* {
        char* p = ws + off;
        off += (bytes + 255) & ~(size_t)255;
        return p;
    };
    float*          dinv   = (float*)alloc((size_t)N * 4);
    int*            counts = (int*)  alloc((size_t)N * 4);
    int*            excl   = (int*)  alloc((size_t)N * 4);
    int*            rowptr = (int*)  alloc((size_t)(N + 1) * 4);
    int*            bsum   = (int*)  alloc(256 * 4);
    int*            rank   = (int*)  alloc((size_t)E * 4);
    int*            csr    = (int*)  alloc((size_t)E * 4);
    unsigned short* Hb     = (unsigned short*)alloc((size_t)N * 128 * 2);
    unsigned short* SKb    = (unsigned short*)alloc((size_t)N * 64 * 2);
    unsigned short* Q0     = (unsigned short*)alloc((size_t)N * 128 * 2);
    unsigned short* P1     = (unsigned short*)alloc((size_t)N * 64 * 2);
    unsigned short* Wt0    = (unsigned short*)alloc(128 * 128 * 2);
    unsigned short* Wt1    = (unsigned short*)alloc(128 * 128 * 2);
    unsigned short* Wt2    = (unsigned short*)alloc(64 * 64 * 2);
    float*          bnS    = (float*)alloc(224 * 4);
    float*          bnO    = (float*)alloc(224 * 4);
    (void)ws_size; (void)n_in; (void)out_size;

    dim3 blk(256);
    auto cdiv = [](int a, int b) { return (a + b - 1) / b; };
    const int nbN = cdiv(N, 256);
    const int RB  = cdiv(E, 1024);
    const int G0  = cdiv(N, 64);

    // ---- init: zero counts + Wt builds + BN fold (zero-LDS) ----
    init_kernel<<<nbN + 64 + 64 + 16 + 1, blk, 0, stream>>>(
        counts, N, nbN, W0, W1, sk1W, W2, sk2W, Wt0, Wt1, Wt2,
        b0v, bn0g, bn0b, bn0m, bn0v,
        b1v, bn1g, bn1b, bn1m, bn1v,
        b2v, bn2g, bn2b, bn2m, bn2v, bnS, bnO);

    // ---- rank hist (zero-LDS, full occupancy) ----
    rank_kernel<<<RB, blk, 0, stream>>>(dst, counts, rank, E);

    // ---- GEMM0 + scan_block tail blocks ----
    gemm0_scan_kernel<<<G0 + nbN, blk, 0, stream>>>(x, Wt0, Hb, N, G0, counts, excl, bsum);

    // ---- CSR finalize ----
    scan_add_kernel<<<cdiv(N + 1, 256), blk, 0, stream>>>(excl, bsum, counts, rowptr, dinv, nbN, N, E);
    fill_csr_kernel<<<cdiv(E, 1024), blk, 0, stream>>>(src, dst, rank, rowptr, csr, E);

    // ---- layer 0 gather: residual = x (f32), out bf16 ----
    gather_bn_kernel<128, true, false, false><<<cdiv(N * 16, 256), blk, 0, stream>>>(
        rowptr, csr, Hb, dinv, bnS, bnO, x, Q0, nullptr, nullptr, nullptr, nullptr, N);

    // ---- layer 1: 128 -> 64, skip fused (bf16) ----
    mfma_gemm_kernel<128, 64, 64, true><<<cdiv(N, 64), blk, 0, stream>>>(
        nullptr, Q0, Wt1, sk1b, Hb, SKb, N);
    gather_bn_kernel<64, true, true, false><<<cdiv(N * 8, 256), blk, 0, stream>>>(
        rowptr, csr, Hb, dinv, bnS + 128, bnO + 128, SKb, P1,
        nullptr, nullptr, nullptr, nullptr, N);

    // ---- layer 2: 64 -> 32, skip fused (bf16), classifier fused ----
    mfma_gemm_kernel<64, 32, 32, true><<<cdiv(N, 128), blk, 0, stream>>>(
        nullptr, P1, Wt2, sk2b, Hb, SKb, N);
    gather_bn_kernel<32, false, true, true><<<cdiv(N * 4, 256), blk, 0, stream>>>(
        rowptr, csr, Hb, dinv, bnS + 192, bnO + 192, SKb, d_out, c1W, c1b, c2W, c2b, N);
}

// Round 11
// 169.379 us; speedup vs baseline: 1.1096x; 1.0053x over previous
//
#include <hip/hip_runtime.h>
#include <hip/hip_bf16.h>
#include <math.h>

// ---------------------------------------------------------------------------
// AdvancedGCN on MI355X — round 11:
//  * padded CSR: every node segment padded to x4 entries (16B-aligned),
//    pad slots = sentinel src N with dinv[N]=0 (zero contribution).
//    Gather inner loop: uniform, int4 index loads, NO tail code.
//  * init_kernel prefills csr with the sentinel (hides under count zeroing)
// ---------------------------------------------------------------------------

#define BN_EPS 1e-5f

typedef __attribute__((ext_vector_type(8))) short bf16x8;
typedef __attribute__((ext_vector_type(4))) float f32x4;

static __device__ __forceinline__ float bf2f(unsigned int u16) {
    return __uint_as_float(u16 << 16);
}
static __device__ __forceinline__ unsigned short f2bf(float f) {
    unsigned int b = __float_as_uint(f);
    return (unsigned short)((b + 0x7FFFu + ((b >> 16) & 1u)) >> 16);
}
static __device__ __forceinline__ unsigned int pack2(float a, float b) {
    return (unsigned int)f2bf(a) | ((unsigned int)f2bf(b) << 16);
}
static __device__ __forceinline__ void unpack8(uint4 u, float* f) {
    f[0] = bf2f(u.x & 0xffffu); f[1] = bf2f(u.x >> 16);
    f[2] = bf2f(u.y & 0xffffu); f[3] = bf2f(u.y >> 16);
    f[4] = bf2f(u.z & 0xffffu); f[5] = bf2f(u.z >> 16);
    f[6] = bf2f(u.w & 0xffffu); f[7] = bf2f(u.w >> 16);
}
static __device__ __forceinline__ int swz(int row, int kb, int rowb) {
    return row * rowb + (kb ^ ((row & 7) << 4));
}

// ---------------- init: zero counts + Wt + BN fold + csr sentinel ----------
// blocks: [0,nbZero) zero | 64 Wt0 | 64 Wt1 | 16 Wt2 | 1 BN fold | CSB sentinel
__global__ void init_kernel(int* __restrict__ counts, int N, int nbZero,
                            const float* __restrict__ W0,
                            const float* __restrict__ W1, const float* __restrict__ sk1W,
                            const float* __restrict__ W2, const float* __restrict__ sk2W,
                            unsigned short* __restrict__ Wt0,
                            unsigned short* __restrict__ Wt1,
                            unsigned short* __restrict__ Wt2,
                            const float* __restrict__ b0v, const float* __restrict__ bn0g,
                            const float* __restrict__ bn0b, const float* __restrict__ bn0m,
                            const float* __restrict__ bn0v,
                            const float* __restrict__ b1v, const float* __restrict__ bn1g,
                            const float* __restrict__ bn1b, const float* __restrict__ bn1m,
                            const float* __restrict__ bn1v,
                            const float* __restrict__ b2v, const float* __restrict__ bn2g,
                            const float* __restrict__ bn2b, const float* __restrict__ bn2m,
                            const float* __restrict__ bn2v,
                            float* __restrict__ bnS, float* __restrict__ bnO,
                            int* __restrict__ csr, int EPB)
{
    int b = blockIdx.x, tid = threadIdx.x;
    if (b < nbZero) {
        int i = b * 256 + tid;
        if (i < N) counts[i] = 0;
        return;
    }
    b -= nbZero;
    if (b < 64) {                       // Wt0: M=128, K=128
        int idx = b * 256 + tid;
        int m = idx >> 7, k = idx & 127;
        Wt0[idx] = f2bf(W0[(size_t)k * 128 + m]);
        return;
    }
    b -= 64;
    if (b < 64) {                       // Wt1: M=64+64, K=128
        int idx = b * 256 + tid;
        int m = idx >> 7, k = idx & 127;
        float v = (m < 64) ? W1[(size_t)k * 64 + m] : sk1W[(size_t)k * 64 + (m - 64)];
        Wt1[idx] = f2bf(v);
        return;
    }
    b -= 64;
    if (b < 16) {                       // Wt2: M=32+32, K=64
        int idx = b * 256 + tid;
        int m = idx >> 6, k = idx & 63;
        float v = (m < 32) ? W2[(size_t)k * 32 + m] : sk2W[(size_t)k * 32 + (m - 32)];
        Wt2[idx] = f2bf(v);
        return;
    }
    b -= 16;
    if (b == 0) {                       // folded BN
        if (tid < 128) {
            float s = bn0g[tid] * rsqrtf(bn0v[tid] + BN_EPS);
            bnS[tid] = s;
            bnO[tid] = (b0v[tid] - bn0m[tid]) * s + bn0b[tid];
        } else if (tid < 192) {
            int c = tid - 128;
            float s = bn1g[c] * rsqrtf(bn1v[c] + BN_EPS);
            bnS[tid] = s;
            bnO[tid] = (b1v[c] - bn1m[c]) * s + bn1b[c];
        } else if (tid < 224) {
            int c = tid - 192;
            float s = bn2g[c] * rsqrtf(bn2v[c] + BN_EPS);
            bnS[tid] = s;
            bnO[tid] = (b2v[c] - bn2m[c]) * s + bn2b[c];
        }
        return;
    }
    b -= 1;
    {   // csr sentinel prefill
        int idx = (b * 256 + tid) * 4;
        if (idx + 3 < EPB) {
            *(int4*)(csr + idx) = make_int4(N, N, N, N);
        } else {
            for (int i2 = idx; i2 < EPB; ++i2) csr[i2] = N;
        }
    }
}

// ------------------------------ rank hist ----------------------------------
__global__ void rank_kernel(const int* __restrict__ dst, int* __restrict__ counts,
                            int* __restrict__ rank, int E) {
    int base = (blockIdx.x * 256 + threadIdx.x) * 4;
    if (base + 3 < E) {
        int4 d = *(const int4*)(dst + base);
        int4 r;
        r.x = atomicAdd(&counts[d.x], 1);
        r.y = atomicAdd(&counts[d.y], 1);
        r.z = atomicAdd(&counts[d.z], 1);
        r.w = atomicAdd(&counts[d.w], 1);
        *(int4*)(rank + base) = r;
    } else {
        for (int e = base; e < E; ++e) rank[e] = atomicAdd(&counts[dst[e]], 1);
    }
}

// --------------------------- MFMA GEMM body --------------------------------
// H(bf16)[N,M1] = X @ Wc ; SK(bf16)[N,M2] = X @ Wsk + skb (cols M1..M-1)
template <int K, int M1, int M2, bool IN_BF16>
static __device__ __forceinline__ void gemm_body(
    const float* __restrict__ Xf, const unsigned short* __restrict__ Xb,
    const unsigned short* __restrict__ Wt, const float* __restrict__ skb,
    unsigned short* __restrict__ H, unsigned short* __restrict__ SK, int N,
    unsigned char* XsB, unsigned char* WsB, int bid)
{
    constexpr int M    = M1 + M2;
    constexpr int BM   = 8192 / M;
    constexpr int WC   = M / 64;
    constexpr int ROWB = K * 2;
    constexpr int CPR  = K / 8;
    constexpr int WCH  = (M * K) / 2048;

    const int tid = threadIdx.x;
    const int r0  = bid * BM;

#pragma unroll
    for (int c = 0; c < 4; ++c) {           // BM*K/2048 == 4 for all layers
        int q   = tid + 256 * c;
        int row = q / CPR, kq = q % CPR;
        int grow = r0 + row;
        uint4 u = make_uint4(0u, 0u, 0u, 0u);
        if (IN_BF16) {
            if (grow < N) u = *(const uint4*)(Xb + (size_t)grow * K + kq * 8);
        } else {
            if (grow < N) {
                const float* p = Xf + (size_t)grow * K + kq * 8;
                float4 v0 = *(const float4*)p;
                float4 v1 = *(const float4*)(p + 4);
                u.x = pack2(v0.x, v0.y); u.y = pack2(v0.z, v0.w);
                u.z = pack2(v1.x, v1.y); u.w = pack2(v1.z, v1.w);
            }
        }
        *(uint4*)(XsB + swz(row, kq * 16, ROWB)) = u;
    }
#pragma unroll
    for (int c = 0; c < WCH; ++c) {
        int q = tid + 256 * c;
        int m = q / CPR, kq = q % CPR;
        uint4 u = *(const uint4*)(Wt + (size_t)m * K + kq * 8);
        *(uint4*)(WsB + swz(m, kq * 16, ROWB)) = u;
    }
    __syncthreads();

    const int lane = tid & 63, wid = tid >> 6;
    const int wr = wid / WC, wc = wid % WC;
    const int lrow = lane & 15;
    const int kb   = (lane >> 4) << 4;

    f32x4 acc[2][4];
#pragma unroll
    for (int fi = 0; fi < 2; ++fi)
#pragma unroll
        for (int fj = 0; fj < 4; ++fj)
            acc[fi][fj] = (f32x4){0.f, 0.f, 0.f, 0.f};

#pragma unroll
    for (int ks = 0; ks < K / 32; ++ks) {
        const int kb0 = ks * 64 + kb;
        bf16x8 a0 = *(const bf16x8*)(XsB + swz(wr * 32 +      lrow, kb0, ROWB));
        bf16x8 a1 = *(const bf16x8*)(XsB + swz(wr * 32 + 16 + lrow, kb0, ROWB));
        bf16x8 b0 = *(const bf16x8*)(WsB + swz(wc * 64 +      lrow, kb0, ROWB));
        bf16x8 b1 = *(const bf16x8*)(WsB + swz(wc * 64 + 16 + lrow, kb0, ROWB));
        bf16x8 b2 = *(const bf16x8*)(WsB + swz(wc * 64 + 32 + lrow, kb0, ROWB));
        bf16x8 b3 = *(const bf16x8*)(WsB + swz(wc * 64 + 48 + lrow, kb0, ROWB));
        acc[0][0] = __builtin_amdgcn_mfma_f32_16x16x32_bf16(a0, b0, acc[0][0], 0, 0, 0);
        acc[0][1] = __builtin_amdgcn_mfma_f32_16x16x32_bf16(a0, b1, acc[0][1], 0, 0, 0);
        acc[0][2] = __builtin_amdgcn_mfma_f32_16x16x32_bf16(a0, b2, acc[0][2], 0, 0, 0);
        acc[0][3] = __builtin_amdgcn_mfma_f32_16x16x32_bf16(a0, b3, acc[0][3], 0, 0, 0);
        acc[1][0] = __builtin_amdgcn_mfma_f32_16x16x32_bf16(a1, b0, acc[1][0], 0, 0, 0);
        acc[1][1] = __builtin_amdgcn_mfma_f32_16x16x32_bf16(a1, b1, acc[1][1], 0, 0, 0);
        acc[1][2] = __builtin_amdgcn_mfma_f32_16x16x32_bf16(a1, b2, acc[1][2], 0, 0, 0);
        acc[1][3] = __builtin_amdgcn_mfma_f32_16x16x32_bf16(a1, b3, acc[1][3], 0, 0, 0);
    }

    const int orow0 = r0 + wr * 32 + (lane >> 4) * 4;
#pragma unroll
    for (int fi = 0; fi < 2; ++fi) {
#pragma unroll
        for (int fj = 0; fj < 4; ++fj) {
            const int col = wc * 64 + fj * 16 + lrow;
            const bool conv = (M2 == 0) || (col < M1);
            const float sb = conv ? 0.f : skb[col - M1];
#pragma unroll
            for (int r = 0; r < 4; ++r) {
                const int row = orow0 + fi * 16 + r;
                if (row >= N) continue;
                const float val = acc[fi][fj][r];
                if (conv) H[(size_t)row * M1 + col] = f2bf(val);
                else      SK[(size_t)row * M2 + (col - M1)] = f2bf(val + sb);
            }
        }
    }
}

// plain GEMM kernels (layers 1,2)
template <int K, int M1, int M2, bool IN_BF16>
__launch_bounds__(256)
__global__ void mfma_gemm_kernel(const float* __restrict__ Xf,
                                 const unsigned short* __restrict__ Xb,
                                 const unsigned short* __restrict__ Wt,
                                 const float* __restrict__ skb,
                                 unsigned short* __restrict__ H,
                                 unsigned short* __restrict__ SK, int N)
{
    constexpr int M  = M1 + M2;
    constexpr int BM = 8192 / M;
    __shared__ unsigned char XsB[BM * K * 2];
    __shared__ unsigned char WsB[M * K * 2];
    gemm_body<K, M1, M2, IN_BF16>(Xf, Xb, Wt, skb, H, SK, N, XsB, WsB, blockIdx.x);
}

// GEMM0 + scan_block tail (PADDED counts; LDS aliased onto GEMM's buffers)
__launch_bounds__(256)
__global__ void gemm0_scan_kernel(const float* __restrict__ X,
                                  const unsigned short* __restrict__ Wt,
                                  unsigned short* __restrict__ H, int N, int G0,
                                  const int* __restrict__ counts,
                                  int* __restrict__ excl, int* __restrict__ bsum)
{
    __shared__ unsigned char XsB[64 * 128 * 2];
    __shared__ unsigned char WsB[128 * 128 * 2];
    if (blockIdx.x < G0) {
        gemm_body<128, 128, 0, false>(X, nullptr, Wt, nullptr, H, nullptr, N,
                                      XsB, WsB, blockIdx.x);
        return;
    }
    // scan_block over PADDED counts (counts final: rank_kernel completed)
    int* s = (int*)XsB;
    const int sbid = blockIdx.x - G0;
    const int tid  = threadIdx.x;
    const int i    = sbid * 256 + tid;
    int v = (i < N) ? ((counts[i] + 3) & ~3) : 0;
    s[tid] = v;
    __syncthreads();
#pragma unroll
    for (int off = 1; off < 256; off <<= 1) {
        int t = (tid >= off) ? s[tid - off] : 0;
        __syncthreads();
        s[tid] += t;
        __syncthreads();
    }
    if (i < N) excl[i] = s[tid] - v;
    if (tid == 255) bsum[sbid] = s[255];
}

// --------------------------- CSR finalize ----------------------------------
__global__ void scan_add_kernel(const int* __restrict__ excl, const int* __restrict__ bsum,
                                const int* __restrict__ counts,
                                int* __restrict__ rowptr, float* __restrict__ dinv,
                                int nb, int N) {
    __shared__ int sb[256];
    int tid = threadIdx.x;
    int v = (tid < nb) ? bsum[tid] : 0;
    sb[tid] = v;
    __syncthreads();
#pragma unroll
    for (int off = 1; off < 256; off <<= 1) {
        int t = (tid >= off) ? sb[tid - off] : 0;
        __syncthreads();
        sb[tid] += t;
        __syncthreads();
    }
    int eb = sb[blockIdx.x] - ((blockIdx.x < nb) ? bsum[blockIdx.x] : 0);  // exclusive
    int i = blockIdx.x * 256 + tid;
    if (i < N) {
        rowptr[i] = excl[i] + eb;
        dinv[i]   = rsqrtf((float)counts[i] + 1.0f);
    }
    if (i == N) {
        rowptr[N] = sb[nb - 1];   // total padded edges
        dinv[N]   = 0.0f;         // sentinel: zero weight
    }
}

__global__ void fill_csr_kernel(const int* __restrict__ src, const int* __restrict__ dst,
                                const int* __restrict__ rank, const int* __restrict__ rowptr,
                                int* __restrict__ csr, int E) {
    int base = (blockIdx.x * 256 + threadIdx.x) * 4;
    if (base + 3 < E) {
        int4 s = *(const int4*)(src + base);
        int4 d = *(const int4*)(dst + base);
        int4 r = *(const int4*)(rank + base);
        csr[rowptr[d.x] + r.x] = s.x;
        csr[rowptr[d.y] + r.y] = s.y;
        csr[rowptr[d.z] + r.z] = s.z;
        csr[rowptr[d.w] + r.w] = s.w;
    } else {
        for (int e = base; e < E; ++e) csr[rowptr[dst[e]] + rank[e]] = src[e];
    }
}

// ------------------ fused gather + self + BN + ReLU + residual -------------
// 8 channels (16B) per thread; padded CSR -> uniform int4-index loop, no tail.
template <int M, bool OUT_BF16, bool RES_BF16, bool CLS>
__launch_bounds__(256)
__global__ void gather_bn_kernel(const int* __restrict__ rowptr, const int* __restrict__ csr,
                                 const unsigned short* __restrict__ H,
                                 const float* __restrict__ dinv,
                                 const float* __restrict__ bnS, const float* __restrict__ bnO,
                                 const void* __restrict__ res, void* __restrict__ out,
                                 const float* __restrict__ cW1, const float* __restrict__ cB1,
                                 const float* __restrict__ cW2, const float* __restrict__ cB2,
                                 int N)
{
    constexpr int TPN = M / 8;
    __shared__ float w1s[512];
    __shared__ float b1s[16];
    __shared__ float w2s[32];
    __shared__ float b2s[2];

    const int tid = threadIdx.x;
    if constexpr (CLS) {
        w1s[tid]       = cW1[tid];
        w1s[tid + 256] = cW1[tid + 256];
        if (tid < 16) b1s[tid] = cB1[tid];
        if (tid < 32) w2s[tid] = cW2[tid];
        if (tid < 2)  b2s[tid] = cB2[tid];
        __syncthreads();
    }

    int gid = blockIdx.x * 256 + tid;
    int n = gid / TPN;
    if (n >= N) return;
    const int c = (gid % TPN) * 8;

    float s[8], o[8];
    {
        float4 sa = *(const float4*)&bnS[c], sb_ = *(const float4*)&bnS[c + 4];
        float4 oa = *(const float4*)&bnO[c], ob_ = *(const float4*)&bnO[c + 4];
        s[0] = sa.x; s[1] = sa.y; s[2] = sa.z; s[3] = sa.w;
        s[4] = sb_.x; s[5] = sb_.y; s[6] = sb_.z; s[7] = sb_.w;
        o[0] = oa.x; o[1] = oa.y; o[2] = oa.z; o[3] = oa.w;
        o[4] = ob_.x; o[5] = ob_.y; o[6] = ob_.z; o[7] = ob_.w;
    }

    const float dn = dinv[n];
    float acc[8], hf[8];
    uint4 hs = *(const uint4*)&H[(size_t)n * M + c];
    unpack8(hs, hf);
    const float d2 = dn * dn;
#pragma unroll
    for (int k = 0; k < 8; ++k) acc[k] = hf[k] * d2;

    // uniform padded loop: every segment is a multiple of 4, 16B-aligned
    const int end = rowptr[n + 1];
    for (int p = rowptr[n]; p < end; p += 4) {
        int4 e = *(const int4*)&csr[p];
        uint4 h0 = *(const uint4*)&H[(size_t)e.x * M + c];
        uint4 h1 = *(const uint4*)&H[(size_t)e.y * M + c];
        uint4 h2 = *(const uint4*)&H[(size_t)e.z * M + c];
        uint4 h3 = *(const uint4*)&H[(size_t)e.w * M + c];
        float w0 = dinv[e.x] * dn, w1 = dinv[e.y] * dn;
        float w2 = dinv[e.z] * dn, w3 = dinv[e.w] * dn;
        float f0[8], f1[8], f2[8], f3[8];
        unpack8(h0, f0); unpack8(h1, f1); unpack8(h2, f2); unpack8(h3, f3);
#pragma unroll
        for (int k = 0; k < 8; ++k) acc[k] = fmaf(f0[k], w0, acc[k]);
#pragma unroll
        for (int k = 0; k < 8; ++k) acc[k] = fmaf(f1[k], w1, acc[k]);
#pragma unroll
        for (int k = 0; k < 8; ++k) acc[k] = fmaf(f2[k], w2, acc[k]);
#pragma unroll
        for (int k = 0; k < 8; ++k) acc[k] = fmaf(f3[k], w3, acc[k]);
    }

    // residual
    float rr[8];
    if constexpr (RES_BF16) {
        const unsigned short* rp = (const unsigned short*)res;
        uint4 r0 = *(const uint4*)&rp[(size_t)n * M + c];
        unpack8(r0, rr);
    } else {
        const float* rp = (const float*)res;
        float4 r0 = *(const float4*)&rp[(size_t)n * M + c];
        float4 r1 = *(const float4*)&rp[(size_t)n * M + c + 4];
        rr[0] = r0.x; rr[1] = r0.y; rr[2] = r0.z; rr[3] = r0.w;
        rr[4] = r1.x; rr[5] = r1.y; rr[6] = r1.z; rr[7] = r1.w;
    }

    float outv[8];
#pragma unroll
    for (int k = 0; k < 8; ++k)
        outv[k] = fmaxf(fmaf(acc[k], s[k], o[k]), 0.f) + rr[k];

    if constexpr (CLS) {
        // partial 32->16 MLP over this thread's 8 channels; 4-lane reduce
        float h[16];
#pragma unroll
        for (int j = 0; j < 16; ++j) h[j] = 0.f;
#pragma unroll
        for (int k = 0; k < 8; ++k)
#pragma unroll
            for (int j = 0; j < 16; ++j)
                h[j] = fmaf(outv[k], w1s[(c + k) * 16 + j], h[j]);
#pragma unroll
        for (int j = 0; j < 16; ++j) {
            h[j] += __shfl_xor(h[j], 1);
            h[j] += __shfl_xor(h[j], 2);
        }
        float z0 = b2s[0], z1 = b2s[1];
#pragma unroll
        for (int j = 0; j < 16; ++j) {
            float r = fmaxf(h[j] + b1s[j], 0.f);
            z0 = fmaf(r, w2s[j * 2 + 0], z0);
            z1 = fmaf(r, w2s[j * 2 + 1], z1);
        }
        if ((tid & 3) == 0) {
            float mx  = fmaxf(z0, z1);
            float lse = mx + logf(expf(z0 - mx) + expf(z1 - mx));
            float* op = (float*)out;
            op[(size_t)n * 2 + 0] = z0 - lse;
            op[(size_t)n * 2 + 1] = z1 - lse;
        }
    } else if constexpr (OUT_BF16) {
        unsigned short* op = (unsigned short*)out;
        uint4 u;
        u.x = pack2(outv[0], outv[1]); u.y = pack2(outv[2], outv[3]);
        u.z = pack2(outv[4], outv[5]); u.w = pack2(outv[6], outv[7]);
        *(uint4*)&op[(size_t)n * M + c] = u;
    } else {
        float* op = (float*)out;
        *(float4*)&op[(size_t)n * M + c]     = make_float4(outv[0], outv[1], outv[2], outv[3]);
        *(float4*)&op[(size_t)n * M + c + 4] = make_float4(outv[4], outv[5], outv[6], outv[7]);
    }
}

// ------------------------------- launch ------------------------------------
extern "C" void kernel_launch(void* const* d_in, const int* in_sizes, int n_in,
                              void* d_out, int out_size, void* d_ws, size_t ws_size,
                              hipStream_t stream)
{
    const float* x    = (const float*)d_in[0];
    const int*   edge = (const int*)d_in[1];
    const float* W0   = (const float*)d_in[2];
    const float* b0v  = (const float*)d_in[3];
    const float* bn0g = (const float*)d_in[4];
    const float* bn0b = (const float*)d_in[5];
    const float* bn0m = (const float*)d_in[6];
    const float* bn0v = (const float*)d_in[7];
    const float* W1   = (const float*)d_in[8];
    const float* b1v  = (const float*)d_in[9];
    const float* bn1g = (const float*)d_in[10];
    const float* bn1b = (const float*)d_in[11];
    const float* bn1m = (const float*)d_in[12];
    const float* bn1v = (const float*)d_in[13];
    const float* sk1W = (const float*)d_in[14];
    const float* sk1b = (const float*)d_in[15];
    const float* W2   = (const float*)d_in[16];
    const float* b2v  = (const float*)d_in[17];
    const float* bn2g = (const float*)d_in[18];
    const float* bn2b = (const float*)d_in[19];
    const float* bn2m = (const float*)d_in[20];
    const float* bn2v = (const float*)d_in[21];
    const float* sk2W = (const float*)d_in[22];
    const float* sk2b = (const float*)d_in[23];
    const float* c1W  = (const float*)d_in[24];
    const float* c1b  = (const float*)d_in[25];
    const float* c2W  = (const float*)d_in[26];
    const float* c2b  = (const float*)d_in[27];

    const int N = in_sizes[0] / 128;
    const int E = in_sizes[1] / 2;
    const int* src = edge;
    const int* dst = edge + E;
    const int EPB = E + 3 * N + 8;   // padded-CSR upper bound

    char*  ws  = (char*)d_ws;
    size_t off = 0;
    auto alloc = [&](size_t bytes) -> char* {
        char* p = ws + off;
        off += (bytes + 255) & ~(size_t)255;
        return p;
    };
    float*          dinv   = (float*)alloc((size_t)(N + 1) * 4);
    int*            counts = (int*)  alloc((size_t)N * 4);
    int*            excl   = (int*)  alloc((size_t)N * 4);
    int*            rowptr = (int*)  alloc((size_t)(N + 1) * 4);
    int*            bsum   = (int*)  alloc(256 * 4);
    int*            rank   = (int*)  alloc((size_t)E * 4);
    int*            csr    = (int*)  alloc((size_t)EPB * 4);
    unsigned short* Hb     = (unsigned short*)alloc((size_t)(N + 1) * 128 * 2);
    unsigned short* SKb    = (unsigned short*)alloc((size_t)N * 64 * 2);
    unsigned short* Q0     = (unsigned short*)alloc((size_t)N * 128 * 2);
    unsigned short* P1     = (unsigned short*)alloc((size_t)N * 64 * 2);
    unsigned short* Wt0    = (unsigned short*)alloc(128 * 128 * 2);
    unsigned short* Wt1    = (unsigned short*)alloc(128 * 128 * 2);
    unsigned short* Wt2    = (unsigned short*)alloc(64 * 64 * 2);
    float*          bnS    = (float*)alloc(224 * 4);
    float*          bnO    = (float*)alloc(224 * 4);
    (void)ws_size; (void)n_in; (void)out_size;

    dim3 blk(256);
    auto cdiv = [](int a, int b) { return (a + b - 1) / b; };
    const int nbN = cdiv(N, 256);
    const int RB  = cdiv(E, 1024);
    const int G0  = cdiv(N, 64);
    const int CSB = cdiv(EPB, 1024);

    // ---- init: zero counts + Wt builds + BN fold + csr sentinel ----
    init_kernel<<<nbN + 64 + 64 + 16 + 1 + CSB, blk, 0, stream>>>(
        counts, N, nbN, W0, W1, sk1W, W2, sk2W, Wt0, Wt1, Wt2,
        b0v, bn0g, bn0b, bn0m, bn0v,
        b1v, bn1g, bn1b, bn1m, bn1v,
        b2v, bn2g, bn2b, bn2m, bn2v, bnS, bnO, csr, EPB);

    // ---- rank hist (zero-LDS, full occupancy) ----
    rank_kernel<<<RB, blk, 0, stream>>>(dst, counts, rank, E);

    // ---- GEMM0 + scan_block tail blocks (padded counts) ----
    gemm0_scan_kernel<<<G0 + nbN, blk, 0, stream>>>(x, Wt0, Hb, N, G0, counts, excl, bsum);

    // ---- CSR finalize ----
    scan_add_kernel<<<cdiv(N + 1, 256), blk, 0, stream>>>(excl, bsum, counts, rowptr, dinv, nbN, N);
    fill_csr_kernel<<<cdiv(E, 1024), blk, 0, stream>>>(src, dst, rank, rowptr, csr, E);

    // ---- layer 0 gather: residual = x (f32), out bf16 ----
    gather_bn_kernel<128, true, false, false><<<cdiv(N * 16, 256), blk, 0, stream>>>(
        rowptr, csr, Hb, dinv, bnS, bnO, x, Q0, nullptr, nullptr, nullptr, nullptr, N);

    // ---- layer 1: 128 -> 64, skip fused (bf16) ----
    mfma_gemm_kernel<128, 64, 64, true><<<cdiv(N, 64), blk, 0, stream>>>(
        nullptr, Q0, Wt1, sk1b, Hb, SKb, N);
    gather_bn_kernel<64, true, true, false><<<cdiv(N * 8, 256), blk, 0, stream>>>(
        rowptr, csr, Hb, dinv, bnS + 128, bnO + 128, SKb, P1,
        nullptr, nullptr, nullptr, nullptr, N);

    // ---- layer 2: 64 -> 32, skip fused (bf16), classifier fused ----
    mfma_gemm_kernel<64, 32, 32, true><<<cdiv(N, 128), blk, 0, stream>>>(
        nullptr, P1, Wt2, sk2b, Hb, SKb, N);
    gather_bn_kernel<32, false, true, true><<<cdiv(N * 4, 256), blk, 0, stream>>>(
        rowptr, csr, Hb, dinv, bnS + 192, bnO + 192, SKb, d_out, c1W, c1b, c2W, c2b, N);
}